// Round 1
// baseline (2176.160 us; speedup 1.0000x reference)
//
#include <hip/hip_runtime.h>
#include <hip/hip_bf16.h>

// B=8, S=4096, D=1024, H=16, DH=64.
//
// Gram-trick restructure (verified algebra, see derivation):
//   G_b = x_b^T x_b                       [1024,1024] per batch   (68.7 GF)
//   M_b = Wq @ G_b                        [1024,1024] per batch   (17.2 GF)
//   scores[b,h,d,e] = (M_b[h*64+d,:] . Wk[h*64+e,:]) / 8          (1.1 GF)
//   att = softmax_e(scores)               [8,16,64,64]
//   T_b[i, h*64+e] = sum_d Wv[h*64+d,i] * att[b,h,d,e]            (1.1 GF)
//   E_b = T_b @ Wo^T                      [1024,1024] per batch   (17.2 GF)
//   out_b = x_b @ E_b                     [4096,1024] per batch   (68.7 GF)
// Q,K,V and the [B,S,D] attention output are never materialized.

#define B_ 8
#define S_ 4096
#define D_ 1024
#define H_ 16

// ---------------- generic fp32 tiled GEMM ----------------
// C[M,N] (+batch) ; A_KM: A stored [K][M]; else [M][K]. B_NK: B stored [N][K]; else [K][N].
// Tile 128x128, BK=16, 256 threads, 8x8 per-thread register tile.
template<bool A_KM, bool B_NK>
__global__ __launch_bounds__(256) void gemm_f32(
    const float* __restrict__ A, const float* __restrict__ B, float* __restrict__ C,
    int M, int N, int K, int lda, int ldb, int ldc,
    long sA, long sB, long sC)
{
    __shared__ float As[16][132];
    __shared__ float Bs[16][132];
    A += (long)blockIdx.z * sA;
    B += (long)blockIdx.z * sB;
    C += (long)blockIdx.z * sC;
    const int bm0 = blockIdx.y * 128, bn0 = blockIdx.x * 128;
    const int t = threadIdx.x;
    const int tn = t & 15, tm = t >> 4;

    float acc[8][8];
#pragma unroll
    for (int i = 0; i < 8; ++i)
#pragma unroll
        for (int j = 0; j < 8; ++j) acc[i][j] = 0.f;

    for (int k0 = 0; k0 < K; k0 += 16) {
        if (k0) __syncthreads();
        // ---- stage A tile into As[k][m] ----
        if (A_KM) {
#pragma unroll
            for (int r = 0; r < 2; ++r) {
                int idx = t + r * 256;
                int row = idx >> 5, c4 = (idx & 31) << 2;
                float4 v = *(const float4*)&A[(long)(k0 + row) * lda + bm0 + c4];
                *(float4*)&As[row][c4] = v;
            }
        } else {
#pragma unroll
            for (int r = 0; r < 2; ++r) {
                int idx = t + r * 256;
                int row = idx >> 2, c4 = (idx & 3) << 2;
                float4 v = *(const float4*)&A[(long)(bm0 + row) * lda + k0 + c4];
                As[c4 + 0][row] = v.x;
                As[c4 + 1][row] = v.y;
                As[c4 + 2][row] = v.z;
                As[c4 + 3][row] = v.w;
            }
        }
        // ---- stage B tile into Bs[k][n] ----
        if (!B_NK) {
#pragma unroll
            for (int r = 0; r < 2; ++r) {
                int idx = t + r * 256;
                int row = idx >> 5, c4 = (idx & 31) << 2;
                float4 v = *(const float4*)&B[(long)(k0 + row) * ldb + bn0 + c4];
                *(float4*)&Bs[row][c4] = v;
            }
        } else {
#pragma unroll
            for (int r = 0; r < 2; ++r) {
                int idx = t + r * 256;
                int row = idx >> 2, c4 = (idx & 3) << 2;
                float4 v = *(const float4*)&B[(long)(bn0 + row) * ldb + k0 + c4];
                Bs[c4 + 0][row] = v.x;
                Bs[c4 + 1][row] = v.y;
                Bs[c4 + 2][row] = v.z;
                Bs[c4 + 3][row] = v.w;
            }
        }
        __syncthreads();
#pragma unroll
        for (int k = 0; k < 16; ++k) {
            float a[8], b[8];
            *(float4*)&a[0] = *(const float4*)&As[k][tm * 8];
            *(float4*)&a[4] = *(const float4*)&As[k][tm * 8 + 4];
            *(float4*)&b[0] = *(const float4*)&Bs[k][tn * 8];
            *(float4*)&b[4] = *(const float4*)&Bs[k][tn * 8 + 4];
#pragma unroll
            for (int i = 0; i < 8; ++i)
#pragma unroll
                for (int j = 0; j < 8; ++j)
                    acc[i][j] = fmaf(a[i], b[j], acc[i][j]);
        }
    }
#pragma unroll
    for (int i = 0; i < 8; ++i) {
        long row = (long)(bm0 + tm * 8 + i) * ldc + bn0 + tn * 8;
#pragma unroll
        for (int j = 0; j < 8; j += 4) {
            float4 v = make_float4(acc[i][j], acc[i][j + 1], acc[i][j + 2], acc[i][j + 3]);
            *(float4*)&C[row + j] = v;
        }
    }
}

// ---------------- scores + softmax ----------------
// One block per (b,h). scores[d,e] = (1/8) * sum_j M[b,h*64+d,j] * Wk[h*64+e,j]
// att[b,h,d,e] = softmax over e.
__global__ __launch_bounds__(256) void scores_softmax(
    const float* __restrict__ Mmat, const float* __restrict__ Wk, float* __restrict__ att)
{
    __shared__ float Ms[64][65];
    __shared__ float Ks[64][65];
    __shared__ float Sm[64][65];
    __shared__ float rowm[64], rows[64];
    const int bh = blockIdx.x;
    const int b = bh >> 4, h = bh & 15;
    const float* Mbase = Mmat + ((long)b * D_ + h * 64) * D_;
    const float* Kbase = Wk + (long)h * 64 * D_;
    const int t = threadIdx.x;
    const int e = t & 63, dg = t >> 6;  // dg in [0,4)

    float acc[16];
#pragma unroll
    for (int i = 0; i < 16; ++i) acc[i] = 0.f;

    for (int kc = 0; kc < D_; kc += 64) {
        __syncthreads();
        {
            int row = t >> 2, c4 = (t & 3) * 16;
#pragma unroll
            for (int r = 0; r < 4; ++r) {
                float4 v = *(const float4*)&Mbase[(long)row * D_ + kc + c4 + r * 4];
                Ms[row][c4 + r * 4 + 0] = v.x;
                Ms[row][c4 + r * 4 + 1] = v.y;
                Ms[row][c4 + r * 4 + 2] = v.z;
                Ms[row][c4 + r * 4 + 3] = v.w;
                float4 w = *(const float4*)&Kbase[(long)row * D_ + kc + c4 + r * 4];
                Ks[row][c4 + r * 4 + 0] = w.x;
                Ks[row][c4 + r * 4 + 1] = w.y;
                Ks[row][c4 + r * 4 + 2] = w.z;
                Ks[row][c4 + r * 4 + 3] = w.w;
            }
        }
        __syncthreads();
#pragma unroll 8
        for (int kk = 0; kk < 64; ++kk) {
            float kv = Ks[e][kk];
#pragma unroll
            for (int dd = 0; dd < 16; ++dd)
                acc[dd] = fmaf(Ms[dg * 16 + dd][kk], kv, acc[dd]);
        }
    }
    __syncthreads();
#pragma unroll
    for (int dd = 0; dd < 16; ++dd) Sm[dg * 16 + dd][e] = acc[dd] * 0.125f;
    __syncthreads();
    if (t < 64) {
        float m = -1e30f;
        for (int ee = 0; ee < 64; ++ee) m = fmaxf(m, Sm[t][ee]);
        float s = 0.f;
        for (int ee = 0; ee < 64; ++ee) s += expf(Sm[t][ee] - m);
        rowm[t] = m;
        rows[t] = 1.0f / s;
    }
    __syncthreads();
    float* abase = att + (long)bh * 64 * 64;
#pragma unroll
    for (int dd = 0; dd < 16; ++dd) {
        int d = dg * 16 + dd;
        abase[d * 64 + e] = expf(Sm[d][e] - rowm[d]) * rows[d];
    }
}

// ---------------- T build ----------------
// T_b[i, h*64+e] = sum_d Wv[h*64+d, i] * att[b,h,d,e]
// grid: (i-tile 0..15, h, b); block 256.
__global__ __launch_bounds__(256) void build_T(
    const float* __restrict__ Wv, const float* __restrict__ att, float* __restrict__ T)
{
    __shared__ float atts[64][65];
    __shared__ float Wvs[64][65];  // [d][ii]
    const int i0 = blockIdx.x * 64, h = blockIdx.y, b = blockIdx.z;
    const int t = threadIdx.x;
    {
        int row = t >> 2, c4 = (t & 3) * 16;
        const float* ab = att + (((long)b * H_ + h) * 64) * 64;
        const float* wb = Wv + (long)h * 64 * D_ + i0;
#pragma unroll
        for (int r = 0; r < 4; ++r) {
            float4 v = *(const float4*)&ab[row * 64 + c4 + r * 4];
            atts[row][c4 + r * 4 + 0] = v.x;
            atts[row][c4 + r * 4 + 1] = v.y;
            atts[row][c4 + r * 4 + 2] = v.z;
            atts[row][c4 + r * 4 + 3] = v.w;
            float4 w = *(const float4*)&wb[(long)row * D_ + c4 + r * 4];
            Wvs[row][c4 + r * 4 + 0] = w.x;
            Wvs[row][c4 + r * 4 + 1] = w.y;
            Wvs[row][c4 + r * 4 + 2] = w.z;
            Wvs[row][c4 + r * 4 + 3] = w.w;
        }
    }
    __syncthreads();
    const int e = t & 63, ig = t >> 6;
    float acc[16];
#pragma unroll
    for (int i = 0; i < 16; ++i) acc[i] = 0.f;
#pragma unroll 8
    for (int d = 0; d < 64; ++d) {
        float av = atts[d][e];
#pragma unroll
        for (int ii = 0; ii < 16; ++ii)
            acc[ii] = fmaf(Wvs[d][ig * 16 + ii], av, acc[ii]);
    }
    float* Tb = T + (long)b * D_ * D_;
#pragma unroll
    for (int ii = 0; ii < 16; ++ii) {
        int i = i0 + ig * 16 + ii;
        Tb[(long)i * D_ + h * 64 + e] = acc[ii];
    }
}

extern "C" void kernel_launch(void* const* d_in, const int* in_sizes, int n_in,
                              void* d_out, int out_size, void* d_ws, size_t ws_size,
                              hipStream_t stream) {
    const float* x  = (const float*)d_in[0];
    const float* Wq = (const float*)d_in[1];
    const float* Wk = (const float*)d_in[2];
    const float* Wv = (const float*)d_in[3];
    const float* Wo = (const float*)d_in[4];
    float* out = (float*)d_out;

    const long MM = (long)D_ * D_;           // 1M floats
    float* bufA = (float*)d_ws;              // G, later T   (8 * 1M floats)
    float* bufB = bufA + (long)B_ * MM;      // M, later E   (8 * 1M floats)
    float* attw = bufB + (long)B_ * MM;      // att          (8*16*64*64)

    const long sX = (long)S_ * D_;

    // 1. G_b = x_b^T x_b   (A=[K=S][M=D], B=[K=S][N=D])
    gemm_f32<true, false><<<dim3(D_ / 128, D_ / 128, B_), 256, 0, stream>>>(
        x, x, bufA, D_, D_, S_, D_, D_, D_, sX, sX, MM);

    // 2. M_b = Wq @ G_b    (A=[M][K] Wq, B=[K][N] G)
    gemm_f32<false, false><<<dim3(D_ / 128, D_ / 128, B_), 256, 0, stream>>>(
        Wq, bufA, bufB, D_, D_, D_, D_, D_, D_, 0, MM, MM);

    // 3. scores + softmax -> att
    scores_softmax<<<B_ * H_, 256, 0, stream>>>(bufB, Wk, attw);

    // 4. T_b (overwrites G in bufA)
    build_T<<<dim3(D_ / 64, H_, B_), 256, 0, stream>>>(Wv, attw, bufA);

    // 5. E_b = T_b @ Wo^T  (A=[M][K] T, B=[N][K] Wo) (overwrites M in bufB)
    gemm_f32<false, true><<<dim3(D_ / 128, D_ / 128, B_), 256, 0, stream>>>(
        bufA, Wo, bufB, D_, D_, D_, D_, D_, D_, MM, 0, MM);

    // 6. out_b = x_b @ E_b
    gemm_f32<false, false><<<dim3(D_ / 128, S_ / 128, B_), 256, 0, stream>>>(
        x, bufB, out, S_, D_, D_, D_, D_, D_, sX, MM, sX);
}

// Round 2
// 1574.031 us; speedup vs baseline: 1.3825x; 1.3825x over previous
//
#include <hip/hip_runtime.h>
#include <hip/hip_bf16.h>

// B=8, S=4096, D=1024, H=16, DH=64.
//
// Gram-trick (validated R1):
//   G_b = x_b^T x_b            [split bf16x2 MFMA: hh+hl+lh]     206 GF
//   Mt_b = G_b @ Wq^T (=M^T)   [split bf16x2 MFMA]               51.5 GF
//   scores[d,e] = Mt[:,h64+d].Wk[h64+e,:]/8 ; softmax  (fp32)    ~1 GF
//   T_b[i,h64+e] = sum_d Wv[h64+d,i] att[d,e]          (fp32)    ~1 GF
//   Et_b[j][i] = sum_k Wo[j,k] T_b[i,k]  (=E^T)  [plain bf16]    17.2 GF
//   out_b = x_b @ E = A-rows(x) x B-rows(Et)     [plain bf16]    68.7 GF

#define B_ 8
#define S_ 4096
#define D_ 1024
#define H_ 16

typedef __attribute__((ext_vector_type(4))) short short4v;
typedef __attribute__((ext_vector_type(8))) short short8v;
typedef __attribute__((ext_vector_type(4))) float f32x4;

__device__ __forceinline__ unsigned short f2bf(float f) {
    unsigned u = __builtin_bit_cast(unsigned, f);
    u += 0x7FFFu + ((u >> 16) & 1u);   // round-to-nearest-even
    return (unsigned short)(u >> 16);
}
__device__ __forceinline__ float bf2f(unsigned short s) {
    unsigned u = (unsigned)s << 16;
    return __builtin_bit_cast(float, u);
}

// ---------------- MFMA GEMM ----------------
// C[M,N] += A x B. TRANS=false: A=[M][K], B=[N][K] row-major (C[m][n]=sum_k A[m][k]B[n][k]).
// TRANS=true:  A=[K][M], B=[K][N] (C[m][n]=sum_k A[k][m]B[k][n])  -- the Gram case.
// SPLIT: fp32 -> hi/lo bf16 pair, 3 MFMA products (hh+hl+lh).
// Tile 128x128, BK=32, 256 thr = 4 waves of 64x64, 4x4 frags of 16x16x32.
template<bool TRANS, bool SPLIT>
__global__ __launch_bounds__(256) void gemm_mfma(
    const float* __restrict__ A, const float* __restrict__ B, float* __restrict__ C,
    int K, int lda, int ldb, int ldc, long sA, long sB, long sC)
{
    constexpr int LDSP = 40;          // padded row stride (shorts): 80B -> spread banks
    constexpr int BUFE = 128 * LDSP;  // one operand buffer (shorts)
    __shared__ short As[(SPLIT ? 2 : 1) * BUFE];
    __shared__ short Bs[(SPLIT ? 2 : 1) * BUFE];

    A += (long)blockIdx.z * sA;
    B += (long)blockIdx.z * sB;
    C += (long)blockIdx.z * sC;
    const int bm0 = blockIdx.y * 128, bn0 = blockIdx.x * 128;
    const int t = threadIdx.x;
    const int lane = t & 63, wave = t >> 6;
    const int wm = (wave >> 1) * 64, wn = (wave & 1) * 64;
    const int fr = lane & 15, kg = lane >> 4;

    f32x4 acc[4][4];
#pragma unroll
    for (int i = 0; i < 4; ++i)
#pragma unroll
        for (int j = 0; j < 4; ++j) acc[i][j] = (f32x4){0.f, 0.f, 0.f, 0.f};

    for (int k0 = 0; k0 < K; k0 += 32) {
        if (k0) __syncthreads();
        // ---------------- stage (fp32 -> bf16 hi[/lo]) ----------------
        if (!TRANS) {
#pragma unroll
            for (int r = 0; r < 4; ++r) {
                const int idx = t + r * 256;
                const int row = idx >> 3, c4 = (idx & 7) << 2;
                float4 va = *(const float4*)&A[(long)(bm0 + row) * lda + k0 + c4];
                float4 vb = *(const float4*)&B[(long)(bn0 + row) * ldb + k0 + c4];
                short4v ha = {(short)f2bf(va.x), (short)f2bf(va.y), (short)f2bf(va.z), (short)f2bf(va.w)};
                short4v hb = {(short)f2bf(vb.x), (short)f2bf(vb.y), (short)f2bf(vb.z), (short)f2bf(vb.w)};
                *(short4v*)&As[row * LDSP + c4] = ha;
                *(short4v*)&Bs[row * LDSP + c4] = hb;
                if (SPLIT) {
                    short4v la = {(short)f2bf(va.x - bf2f(ha[0])), (short)f2bf(va.y - bf2f(ha[1])),
                                  (short)f2bf(va.z - bf2f(ha[2])), (short)f2bf(va.w - bf2f(ha[3]))};
                    short4v lb = {(short)f2bf(vb.x - bf2f(hb[0])), (short)f2bf(vb.y - bf2f(hb[1])),
                                  (short)f2bf(vb.z - bf2f(hb[2])), (short)f2bf(vb.w - bf2f(hb[3]))};
                    *(short4v*)&As[BUFE + row * LDSP + c4] = la;
                    *(short4v*)&Bs[BUFE + row * LDSP + c4] = lb;
                }
            }
        } else {
#pragma unroll
            for (int r = 0; r < 4; ++r) {
                const int idx = t + r * 256;
                const int kk = idx >> 5, m4 = (idx & 31) << 2;
                float4 va = *(const float4*)&A[(long)(k0 + kk) * lda + bm0 + m4];
                float4 vb = *(const float4*)&B[(long)(k0 + kk) * ldb + bn0 + m4];
                float fa[4] = {va.x, va.y, va.z, va.w};
                float fb[4] = {vb.x, vb.y, vb.z, vb.w};
#pragma unroll
                for (int j = 0; j < 4; ++j) {
                    unsigned short ha = f2bf(fa[j]);
                    unsigned short hb = f2bf(fb[j]);
                    As[(m4 + j) * LDSP + kk] = (short)ha;
                    Bs[(m4 + j) * LDSP + kk] = (short)hb;
                    if (SPLIT) {
                        As[BUFE + (m4 + j) * LDSP + kk] = (short)f2bf(fa[j] - bf2f(ha));
                        Bs[BUFE + (m4 + j) * LDSP + kk] = (short)f2bf(fb[j] - bf2f(hb));
                    }
                }
            }
        }
        __syncthreads();

        // ---------------- frags + MFMA ----------------
        const int ab = (wm + fr) * LDSP + kg * 8;
        const int bbo = (wn + fr) * LDSP + kg * 8;
        short8v af[4], bfv[4];
#pragma unroll
        for (int mt = 0; mt < 4; ++mt) af[mt] = *(const short8v*)&As[ab + mt * 16 * LDSP];
        if (!SPLIT) {
#pragma unroll
            for (int nt = 0; nt < 4; ++nt) bfv[nt] = *(const short8v*)&Bs[bbo + nt * 16 * LDSP];
#pragma unroll
            for (int mt = 0; mt < 4; ++mt)
#pragma unroll
                for (int nt = 0; nt < 4; ++nt)
                    acc[mt][nt] = __builtin_amdgcn_mfma_f32_16x16x32_bf16(af[mt], bfv[nt], acc[mt][nt], 0, 0, 0);
        } else {
            // a_hi * b_lo
#pragma unroll
            for (int nt = 0; nt < 4; ++nt) bfv[nt] = *(const short8v*)&Bs[BUFE + bbo + nt * 16 * LDSP];
#pragma unroll
            for (int mt = 0; mt < 4; ++mt)
#pragma unroll
                for (int nt = 0; nt < 4; ++nt)
                    acc[mt][nt] = __builtin_amdgcn_mfma_f32_16x16x32_bf16(af[mt], bfv[nt], acc[mt][nt], 0, 0, 0);
            // a_hi * b_hi
#pragma unroll
            for (int nt = 0; nt < 4; ++nt) bfv[nt] = *(const short8v*)&Bs[bbo + nt * 16 * LDSP];
#pragma unroll
            for (int mt = 0; mt < 4; ++mt)
#pragma unroll
                for (int nt = 0; nt < 4; ++nt)
                    acc[mt][nt] = __builtin_amdgcn_mfma_f32_16x16x32_bf16(af[mt], bfv[nt], acc[mt][nt], 0, 0, 0);
            // a_lo * b_hi
#pragma unroll
            for (int mt = 0; mt < 4; ++mt) af[mt] = *(const short8v*)&As[BUFE + ab + mt * 16 * LDSP];
#pragma unroll
            for (int mt = 0; mt < 4; ++mt)
#pragma unroll
                for (int nt = 0; nt < 4; ++nt)
                    acc[mt][nt] = __builtin_amdgcn_mfma_f32_16x16x32_bf16(af[mt], bfv[nt], acc[mt][nt], 0, 0, 0);
        }
    }

    // C/D layout (m89-verified): col = lane&15, row = (lane>>4)*4 + q
#pragma unroll
    for (int mt = 0; mt < 4; ++mt)
#pragma unroll
        for (int nt = 0; nt < 4; ++nt)
#pragma unroll
            for (int q = 0; q < 4; ++q) {
                const int row = bm0 + wm + mt * 16 + kg * 4 + q;
                const int col = bn0 + wn + nt * 16 + fr;
                C[(long)row * ldc + col] = acc[mt][nt][q];
            }
}

// ---------------- scores + softmax (fp32, reads Mt) ----------------
// scores[d,e] = (1/8) * sum_j Mt[j][h64+d] * Wk[h64+e][j];  att = softmax_e.
__global__ __launch_bounds__(256) void scores_softmax(
    const float* __restrict__ Mt, const float* __restrict__ Wk, float* __restrict__ att)
{
    __shared__ float Ms2[64][65];   // [jj][d]
    __shared__ float Ks[64][65];    // [e][jj]
    __shared__ float Sm[64][65];
    __shared__ float rowm[64], rows[64];
    const int bh = blockIdx.x;
    const int b = bh >> 4, h = bh & 15;
    const float* Mbase = Mt + (long)b * D_ * D_ + h * 64;     // Mt[j][h64+d]
    const float* Kbase = Wk + (long)h * 64 * D_;
    const int t = threadIdx.x;
    const int e = t & 63, dg = t >> 6;

    float acc[16];
#pragma unroll
    for (int i = 0; i < 16; ++i) acc[i] = 0.f;

    for (int jc = 0; jc < D_; jc += 64) {
        __syncthreads();
        {
            int row = t >> 2, c4 = (t & 3) * 16;
#pragma unroll
            for (int r = 0; r < 4; ++r) {
                float4 v = *(const float4*)&Mbase[(long)(jc + row) * D_ + c4 + r * 4];
                Ms2[row][c4 + r * 4 + 0] = v.x;
                Ms2[row][c4 + r * 4 + 1] = v.y;
                Ms2[row][c4 + r * 4 + 2] = v.z;
                Ms2[row][c4 + r * 4 + 3] = v.w;
                float4 w = *(const float4*)&Kbase[(long)row * D_ + jc + c4 + r * 4];
                Ks[row][c4 + r * 4 + 0] = w.x;
                Ks[row][c4 + r * 4 + 1] = w.y;
                Ks[row][c4 + r * 4 + 2] = w.z;
                Ks[row][c4 + r * 4 + 3] = w.w;
            }
        }
        __syncthreads();
#pragma unroll 8
        for (int jj = 0; jj < 64; ++jj) {
            float kv = Ks[e][jj];
#pragma unroll
            for (int dd = 0; dd < 16; ++dd)
                acc[dd] = fmaf(Ms2[jj][dg * 16 + dd], kv, acc[dd]);
        }
    }
    __syncthreads();
#pragma unroll
    for (int dd = 0; dd < 16; ++dd) Sm[dg * 16 + dd][e] = acc[dd] * 0.125f;
    __syncthreads();
    if (t < 64) {
        float m = -1e30f;
        for (int ee = 0; ee < 64; ++ee) m = fmaxf(m, Sm[t][ee]);
        float s = 0.f;
        for (int ee = 0; ee < 64; ++ee) s += expf(Sm[t][ee] - m);
        rowm[t] = m;
        rows[t] = 1.0f / s;
    }
    __syncthreads();
    float* abase = att + (long)bh * 64 * 64;
#pragma unroll
    for (int dd = 0; dd < 16; ++dd) {
        int d = dg * 16 + dd;
        abase[d * 64 + e] = expf(Sm[d][e] - rowm[d]) * rows[d];
    }
}

// ---------------- T build (fp32) ----------------
// T_b[i, h*64+e] = sum_d Wv[h*64+d, i] * att[b,h,d,e]
__global__ __launch_bounds__(256) void build_T(
    const float* __restrict__ Wv, const float* __restrict__ att, float* __restrict__ T)
{
    __shared__ float atts[64][65];
    __shared__ float Wvs[64][65];
    const int i0 = blockIdx.x * 64, h = blockIdx.y, b = blockIdx.z;
    const int t = threadIdx.x;
    {
        int row = t >> 2, c4 = (t & 3) * 16;
        const float* ab = att + (((long)b * H_ + h) * 64) * 64;
        const float* wb = Wv + (long)h * 64 * D_ + i0;
#pragma unroll
        for (int r = 0; r < 4; ++r) {
            float4 v = *(const float4*)&ab[row * 64 + c4 + r * 4];
            atts[row][c4 + r * 4 + 0] = v.x;
            atts[row][c4 + r * 4 + 1] = v.y;
            atts[row][c4 + r * 4 + 2] = v.z;
            atts[row][c4 + r * 4 + 3] = v.w;
            float4 w = *(const float4*)&wb[(long)row * D_ + c4 + r * 4];
            Wvs[row][c4 + r * 4 + 0] = w.x;
            Wvs[row][c4 + r * 4 + 1] = w.y;
            Wvs[row][c4 + r * 4 + 2] = w.z;
            Wvs[row][c4 + r * 4 + 3] = w.w;
        }
    }
    __syncthreads();
    const int e = t & 63, ig = t >> 6;
    float acc[16];
#pragma unroll
    for (int i = 0; i < 16; ++i) acc[i] = 0.f;
#pragma unroll 8
    for (int d = 0; d < 64; ++d) {
        float av = atts[d][e];
#pragma unroll
        for (int ii = 0; ii < 16; ++ii)
            acc[ii] = fmaf(Wvs[d][ig * 16 + ii], av, acc[ii]);
    }
    float* Tb = T + (long)b * D_ * D_;
#pragma unroll
    for (int ii = 0; ii < 16; ++ii) {
        int i = i0 + ig * 16 + ii;
        Tb[(long)i * D_ + h * 64 + e] = acc[ii];
    }
}

extern "C" void kernel_launch(void* const* d_in, const int* in_sizes, int n_in,
                              void* d_out, int out_size, void* d_ws, size_t ws_size,
                              hipStream_t stream) {
    const float* x  = (const float*)d_in[0];
    const float* Wq = (const float*)d_in[1];
    const float* Wk = (const float*)d_in[2];
    const float* Wv = (const float*)d_in[3];
    const float* Wo = (const float*)d_in[4];
    float* out = (float*)d_out;

    const long MM = (long)D_ * D_;
    const long sX = (long)S_ * D_;
    float* bufG = (float*)d_ws;              // G, later T     (8 * 1M f32)
    float* bufM = bufG + (long)B_ * MM;      // Mt, later Et   (8 * 1M f32)
    float* attw = bufM + (long)B_ * MM;      // att            (8*16*64*64)

    // 1. G_b = x_b^T x_b  (TRANS staging, split precision)
    gemm_mfma<true, true><<<dim3(D_ / 128, D_ / 128, B_), 256, 0, stream>>>(
        x, x, bufG, S_, D_, D_, D_, sX, sX, MM);

    // 2. Mt_b = G_b @ Wq^T  (row-major both, split)
    gemm_mfma<false, true><<<dim3(D_ / 128, D_ / 128, B_), 256, 0, stream>>>(
        bufG, Wq, bufM, D_, D_, D_, D_, MM, 0, MM);

    // 3. scores + softmax -> att (fp32)
    scores_softmax<<<B_ * H_, 256, 0, stream>>>(bufM, Wk, attw);

    // 4. T_b (fp32; overwrites G)
    build_T<<<dim3(D_ / 64, H_, B_), 256, 0, stream>>>(Wv, attw, bufG);

    // 5. Et_b[j][i] = sum_k Wo[j][k] T_b[i][k]  (plain bf16; overwrites Mt)
    gemm_mfma<false, false><<<dim3(D_ / 128, D_ / 128, B_), 256, 0, stream>>>(
        Wo, bufG, bufM, D_, D_, D_, D_, 0, MM, MM);

    // 6. out_b[s][j] = sum_i x_b[s][i] Et_b[j][i]  (plain bf16)
    gemm_mfma<false, false><<<dim3(D_ / 128, S_ / 128, B_), 256, 0, stream>>>(
        x, bufM, out, D_, D_, D_, D_, sX, MM, sX);
}

// Round 3
// 712.540 us; speedup vs baseline: 3.0541x; 2.2090x over previous
//
#include <hip/hip_runtime.h>
#include <hip/hip_bf16.h>

// B=8, S=4096, D=1024, H=16, DH=64.
// Pipeline (all conversions hoisted out of GEMMs):
//   prepack: x -> xth,xtl [B][D][S] bf16 hi/lo (in d_out!), x -> xh [B][S][D] bf16,
//            Wq -> Wqh/Wql, Wo -> Woh
//   G  = Xt Xt^T (split bf16x2, SYM lower-triangle)  -> Gh,Gl bf16      206*0.56 GF
//   Mt = G @ Wq^T (split)                            -> Mt fp32         51.5 GF
//   scores/softmax (fp32 VALU)                       -> att
//   T build (fp32 VALU)                              -> Th bf16
//   Et = Wo x T-rows (plain bf16)                    -> Eth bf16        17.2 GF
//   out = x @ E (plain bf16)                         -> out fp32        68.7 GF

#define B_ 8
#define S_ 4096
#define D_ 1024
#define H_ 16

typedef unsigned short u16;
typedef __attribute__((ext_vector_type(4))) short short4v;
typedef __attribute__((ext_vector_type(8))) short short8v;
typedef __attribute__((ext_vector_type(4))) float f32x4;

typedef __attribute__((address_space(3))) unsigned lds_u32_t;
typedef const __attribute__((address_space(1))) unsigned glb_u32_t;

__device__ __forceinline__ unsigned short f2bf(float f) {
    unsigned u = __builtin_bit_cast(unsigned, f);
    u += 0x7FFFu + ((u >> 16) & 1u);
    return (unsigned short)(u >> 16);
}
__device__ __forceinline__ float bf2f(unsigned short s) {
    unsigned u = (unsigned)s << 16;
    return __builtin_bit_cast(float, u);
}

__device__ __forceinline__ void gll16(const u16* g, u16* lds) {
    __builtin_amdgcn_global_load_lds((glb_u32_t*)g, (lds_u32_t*)lds, 16, 0, 0);
}

// ---------------- unified MFMA GEMM (m97 structure) ----------------
// C[m][n] = sum_k A[m][k] * B[n][k], both operands row-major [row][K] bf16.
// SPLIT: + A_hi*B_lo + A_lo*B_hi.  SYM: skip upper blocks, mirror-write.
// OUT: 0 = fp32, 1 = bf16 hi, 2 = bf16 hi+lo.
template<int OUT, bool SPLIT, bool SYM>
__global__ __launch_bounds__(256) void gemm_bf16(
    const u16* __restrict__ Ah, const u16* __restrict__ Al,
    const u16* __restrict__ Bh, const u16* __restrict__ Bl,
    float* __restrict__ Cf, u16* __restrict__ Ch, u16* __restrict__ Cl,
    int K, int lda, int ldb, int ldc, long sA, long sB, long sC)
{
    __shared__ u16 As[(SPLIT ? 2 : 1) * 128 * 32];
    __shared__ u16 Bs[(SPLIT ? 2 : 1) * 128 * 32];

    const int bn0 = blockIdx.x * 128, bm0 = blockIdx.y * 128;
    if (SYM && bm0 < bn0) return;
    const int t = threadIdx.x, lane = t & 63, wave = t >> 6;
    const int wm = (wave >> 1) * 64, wn = (wave & 1) * 64;
    const int fr = lane & 15, kg = lane >> 4;

    const u16* Agh = Ah + (long)blockIdx.z * sA + (long)bm0 * lda;
    const u16* Bgh = Bh + (long)blockIdx.z * sB + (long)bn0 * ldb;
    const u16* Agl = SPLIT ? (Al + (long)blockIdx.z * sA + (long)bm0 * lda) : nullptr;
    const u16* Bgl = SPLIT ? (Bl + (long)blockIdx.z * sB + (long)bn0 * ldb) : nullptr;

    f32x4 acc[4][4];
#pragma unroll
    for (int i = 0; i < 4; ++i)
#pragma unroll
        for (int j = 0; j < 4; ++j) acc[i][j] = (f32x4){0.f, 0.f, 0.f, 0.f};

    for (int k0 = 0; k0 < K; k0 += 32) {
        if (k0) __syncthreads();
        // stage 128x32 bf16 tiles, linear LDS, 16B direct-to-LDS
#pragma unroll
        for (int r = 0; r < 2; ++r) {
            const int off = r * 2048 + t * 8;   // shorts
            const int row = off >> 5, kc = off & 31;
            gll16(Agh + (long)row * lda + k0 + kc, As + off);
            gll16(Bgh + (long)row * ldb + k0 + kc, Bs + off);
            if (SPLIT) {
                gll16(Agl + (long)row * lda + k0 + kc, As + 4096 + off);
                gll16(Bgl + (long)row * ldb + k0 + kc, Bs + 4096 + off);
            }
        }
        __syncthreads();

        const int ao = (wm + fr) * 32 + kg * 8;
        const int bo = (wn + fr) * 32 + kg * 8;
        short8v a[4], b[4];
#pragma unroll
        for (int mt = 0; mt < 4; ++mt) a[mt] = *(const short8v*)&As[ao + mt * 512];
#pragma unroll
        for (int nt = 0; nt < 4; ++nt) b[nt] = *(const short8v*)&Bs[bo + nt * 512];
#pragma unroll
        for (int mt = 0; mt < 4; ++mt)
#pragma unroll
            for (int nt = 0; nt < 4; ++nt)
                acc[mt][nt] = __builtin_amdgcn_mfma_f32_16x16x32_bf16(a[mt], b[nt], acc[mt][nt], 0, 0, 0);
        if (SPLIT) {
            short8v bl[4];
#pragma unroll
            for (int nt = 0; nt < 4; ++nt) bl[nt] = *(const short8v*)&Bs[4096 + bo + nt * 512];
#pragma unroll
            for (int mt = 0; mt < 4; ++mt)
#pragma unroll
                for (int nt = 0; nt < 4; ++nt)
                    acc[mt][nt] = __builtin_amdgcn_mfma_f32_16x16x32_bf16(a[mt], bl[nt], acc[mt][nt], 0, 0, 0);
#pragma unroll
            for (int mt = 0; mt < 4; ++mt) a[mt] = *(const short8v*)&As[4096 + ao + mt * 512];
#pragma unroll
            for (int mt = 0; mt < 4; ++mt)
#pragma unroll
                for (int nt = 0; nt < 4; ++nt)
                    acc[mt][nt] = __builtin_amdgcn_mfma_f32_16x16x32_bf16(a[mt], b[nt], acc[mt][nt], 0, 0, 0);
        }
    }

    // C/D layout: col = lane&15, row = (lane>>4)*4 + q  (m89-verified)
#pragma unroll
    for (int mt = 0; mt < 4; ++mt)
#pragma unroll
        for (int nt = 0; nt < 4; ++nt)
#pragma unroll
            for (int q = 0; q < 4; ++q) {
                const int row = bm0 + wm + mt * 16 + kg * 4 + q;
                const int col = bn0 + wn + nt * 16 + fr;
                const float v = acc[mt][nt][q];
                const long idx = (long)blockIdx.z * sC + (long)row * ldc + col;
                if (OUT == 0) {
                    Cf[idx] = v;
                } else {
                    const unsigned short h = f2bf(v);
                    Ch[idx] = h;
                    if (OUT == 2) Cl[idx] = (u16)f2bf(v - bf2f(h));
                    if (SYM && bm0 != bn0) {
                        const long m2 = (long)blockIdx.z * sC + (long)col * ldc + row;
                        Ch[m2] = h;
                        if (OUT == 2) Cl[m2] = (u16)f2bf(v - bf2f(h));
                    }
                }
            }
}

// ---------------- prepack: x -> transposed bf16 hi/lo ----------------
// grid (D/64, S/64, B); 64x64 tile transpose through LDS.
__global__ __launch_bounds__(256) void prepack_xt(
    const float* __restrict__ x, u16* __restrict__ xth, u16* __restrict__ xtl)
{
    __shared__ float tile[64][65];
    const int d0 = blockIdx.x * 64, s0 = blockIdx.y * 64, b = blockIdx.z;
    const float* xb = x + (long)b * S_ * D_;
    const int t = threadIdx.x;
    const int sr = t >> 4, dc = (t & 15) * 4;
#pragma unroll
    for (int r = 0; r < 4; ++r) {
        const int s = sr + r * 16;
        float4 v = *(const float4*)&xb[(long)(s0 + s) * D_ + d0 + dc];
        tile[dc + 0][s] = v.x;
        tile[dc + 1][s] = v.y;
        tile[dc + 2][s] = v.z;
        tile[dc + 3][s] = v.w;
    }
    __syncthreads();
    const int dr = t >> 4, sc = (t & 15) * 4;
    u16* th = xth + (long)b * D_ * S_;
    u16* tl = xtl + (long)b * D_ * S_;
#pragma unroll
    for (int r = 0; r < 4; ++r) {
        const int d = dr + r * 16;
        short4v hv, lv;
#pragma unroll
        for (int j = 0; j < 4; ++j) {
            const float v = tile[d][sc + j];
            const unsigned short h = f2bf(v);
            hv[j] = (short)h;
            lv[j] = (short)f2bf(v - bf2f(h));
        }
        *(short4v*)&th[(long)(d0 + d) * S_ + s0 + sc] = hv;
        *(short4v*)&tl[(long)(d0 + d) * S_ + s0 + sc] = lv;
    }
}

// ---------------- generic fp32 -> bf16 convert ----------------
template<bool SP>
__global__ __launch_bounds__(256) void convert_bf16(
    const float* __restrict__ in, u16* __restrict__ h, u16* __restrict__ l, long n)
{
    const long i = ((long)blockIdx.x * 256 + threadIdx.x) * 4;
    if (i >= n) return;
    float4 v = *(const float4*)&in[i];
    float f[4] = {v.x, v.y, v.z, v.w};
    short4v hv, lv;
#pragma unroll
    for (int j = 0; j < 4; ++j) {
        const unsigned short hh = f2bf(f[j]);
        hv[j] = (short)hh;
        lv[j] = (short)f2bf(f[j] - bf2f(hh));
    }
    *(short4v*)&h[i] = hv;
    if (SP) *(short4v*)&l[i] = lv;
}

// ---------------- scores + softmax (fp32) ----------------
__global__ __launch_bounds__(256) void scores_softmax(
    const float* __restrict__ Mt, const float* __restrict__ Wk, float* __restrict__ att)
{
    __shared__ float Ms2[64][65];
    __shared__ float Ks[64][65];
    __shared__ float Sm[64][65];
    __shared__ float rowm[64], rows[64];
    const int bh = blockIdx.x;
    const int b = bh >> 4, h = bh & 15;
    const float* Mbase = Mt + (long)b * D_ * D_ + h * 64;
    const float* Kbase = Wk + (long)h * 64 * D_;
    const int t = threadIdx.x;
    const int e = t & 63, dg = t >> 6;

    float acc[16];
#pragma unroll
    for (int i = 0; i < 16; ++i) acc[i] = 0.f;

    for (int jc = 0; jc < D_; jc += 64) {
        __syncthreads();
        {
            int row = t >> 2, c4 = (t & 3) * 16;
#pragma unroll
            for (int r = 0; r < 4; ++r) {
                float4 v = *(const float4*)&Mbase[(long)(jc + row) * D_ + c4 + r * 4];
                Ms2[row][c4 + r * 4 + 0] = v.x;
                Ms2[row][c4 + r * 4 + 1] = v.y;
                Ms2[row][c4 + r * 4 + 2] = v.z;
                Ms2[row][c4 + r * 4 + 3] = v.w;
                float4 w = *(const float4*)&Kbase[(long)row * D_ + jc + c4 + r * 4];
                Ks[row][c4 + r * 4 + 0] = w.x;
                Ks[row][c4 + r * 4 + 1] = w.y;
                Ks[row][c4 + r * 4 + 2] = w.z;
                Ks[row][c4 + r * 4 + 3] = w.w;
            }
        }
        __syncthreads();
#pragma unroll 8
        for (int jj = 0; jj < 64; ++jj) {
            float kv = Ks[e][jj];
#pragma unroll
            for (int dd = 0; dd < 16; ++dd)
                acc[dd] = fmaf(Ms2[jj][dg * 16 + dd], kv, acc[dd]);
        }
    }
    __syncthreads();
#pragma unroll
    for (int dd = 0; dd < 16; ++dd) Sm[dg * 16 + dd][e] = acc[dd] * 0.125f;
    __syncthreads();
    if (t < 64) {
        float m = -1e30f;
        for (int ee = 0; ee < 64; ++ee) m = fmaxf(m, Sm[t][ee]);
        float s = 0.f;
        for (int ee = 0; ee < 64; ++ee) s += expf(Sm[t][ee] - m);
        rowm[t] = m;
        rows[t] = 1.0f / s;
    }
    __syncthreads();
    float* abase = att + (long)bh * 64 * 64;
#pragma unroll
    for (int dd = 0; dd < 16; ++dd) {
        int d = dg * 16 + dd;
        abase[d * 64 + e] = expf(Sm[d][e] - rowm[d]) * rows[d];
    }
}

// ---------------- T build (fp32 compute, bf16 out) ----------------
__global__ __launch_bounds__(256) void build_T(
    const float* __restrict__ Wv, const float* __restrict__ att, u16* __restrict__ T)
{
    __shared__ float atts[64][65];
    __shared__ float Wvs[64][65];
    const int i0 = blockIdx.x * 64, h = blockIdx.y, b = blockIdx.z;
    const int t = threadIdx.x;
    {
        int row = t >> 2, c4 = (t & 3) * 16;
        const float* ab = att + (((long)b * H_ + h) * 64) * 64;
        const float* wb = Wv + (long)h * 64 * D_ + i0;
#pragma unroll
        for (int r = 0; r < 4; ++r) {
            float4 v = *(const float4*)&ab[row * 64 + c4 + r * 4];
            atts[row][c4 + r * 4 + 0] = v.x;
            atts[row][c4 + r * 4 + 1] = v.y;
            atts[row][c4 + r * 4 + 2] = v.z;
            atts[row][c4 + r * 4 + 3] = v.w;
            float4 w = *(const float4*)&wb[(long)row * D_ + c4 + r * 4];
            Wvs[row][c4 + r * 4 + 0] = w.x;
            Wvs[row][c4 + r * 4 + 1] = w.y;
            Wvs[row][c4 + r * 4 + 2] = w.z;
            Wvs[row][c4 + r * 4 + 3] = w.w;
        }
    }
    __syncthreads();
    const int e = t & 63, ig = t >> 6;
    float acc[16];
#pragma unroll
    for (int i = 0; i < 16; ++i) acc[i] = 0.f;
#pragma unroll 8
    for (int d = 0; d < 64; ++d) {
        float av = atts[d][e];
#pragma unroll
        for (int ii = 0; ii < 16; ++ii)
            acc[ii] = fmaf(Wvs[d][ig * 16 + ii], av, acc[ii]);
    }
    u16* Tb = T + (long)b * D_ * D_;
#pragma unroll
    for (int ii = 0; ii < 16; ++ii) {
        int i = i0 + ig * 16 + ii;
        Tb[(long)i * D_ + h * 64 + e] = f2bf(acc[ii]);
    }
}

extern "C" void kernel_launch(void* const* d_in, const int* in_sizes, int n_in,
                              void* d_out, int out_size, void* d_ws, size_t ws_size,
                              hipStream_t stream) {
    const float* x  = (const float*)d_in[0];
    const float* Wq = (const float*)d_in[1];
    const float* Wk = (const float*)d_in[2];
    const float* Wv = (const float*)d_in[3];
    const float* Wo = (const float*)d_in[4];
    float* out = (float*)d_out;

    const long MM = (long)D_ * D_;          // 1,048,576
    const long XE = (long)B_ * S_ * D_;     // 33,554,432
    const long GE = (long)B_ * MM;          // 8,388,608

    // Transposed bf16 x lives in d_out (exactly 2*XE shorts = out bytes);
    // consumed by the G GEMM before the final GEMM writes `out`.
    u16* xth = (u16*)d_out;
    u16* xtl = xth + XE;

    char* w = (char*)d_ws;
    u16* xh   = (u16*)w;  w += XE * 2;      //  67.1 MB
    u16* Gh   = (u16*)w;  w += GE * 2;      //  16.8 MB (later Th)
    u16* Gl   = (u16*)w;  w += GE * 2;      //  16.8 MB (later Eth)
    float* Mt = (float*)w; w += GE * 4;     //  33.6 MB
    float* att = (float*)w; w += (long)B_ * H_ * 64 * 64 * 4;  // 2.1 MB
    u16* Wqh  = (u16*)w;  w += MM * 2;      //   2.1 MB
    u16* Wql  = (u16*)w;  w += MM * 2;
    u16* Woh  = (u16*)w;  w += MM * 2;
    u16* Th  = Gh;
    u16* Eth = Gl;

    // 1. prepacks
    prepack_xt<<<dim3(D_ / 64, S_ / 64, B_), 256, 0, stream>>>(x, xth, xtl);
    convert_bf16<true ><<<MM / 1024, 256, 0, stream>>>(Wq, Wqh, Wql, MM);
    convert_bf16<false><<<MM / 1024, 256, 0, stream>>>(Wo, Woh, nullptr, MM);

    // 2. G = Xt Xt^T (split, SYM) -> Gh/Gl
    gemm_bf16<2, true, true><<<dim3(8, 8, B_), 256, 0, stream>>>(
        xth, xtl, xth, xtl, nullptr, Gh, Gl,
        S_, S_, S_, D_, (long)D_ * S_, (long)D_ * S_, MM);

    // 3. xh (reuses stream after G no longer needs x... independent anyway)
    convert_bf16<false><<<XE / 1024, 256, 0, stream>>>(x, xh, nullptr, XE);

    // 4. Mt[i][j] = sum_k G[i][k] Wq[j][k]  (split) -> fp32
    gemm_bf16<0, true, false><<<dim3(8, 8, B_), 256, 0, stream>>>(
        Gh, Gl, Wqh, Wql, Mt, nullptr, nullptr,
        D_, D_, D_, D_, MM, 0, MM);

    // 5. scores + softmax
    scores_softmax<<<B_ * H_, 256, 0, stream>>>(Mt, Wk, att);

    // 6. T (bf16) — into Gh region (G consumed)
    build_T<<<dim3(D_ / 64, H_, B_), 256, 0, stream>>>(Wv, att, Th);

    // 7. Et[j][i] = sum_k Wo[j][k] T[i][k]  (plain) -> bf16, into Gl region
    gemm_bf16<1, false, false><<<dim3(8, 8, B_), 256, 0, stream>>>(
        Woh, nullptr, Th, nullptr, nullptr, Eth, nullptr,
        D_, D_, D_, D_, 0, MM, MM);

    // 8. out[s][j] = sum_i x[s][i] Et[j][i]
    gemm_bf16<0, false, false><<<dim3(8, 32, B_), 256, 0, stream>>>(
        xh, nullptr, Eth, nullptr, out, nullptr, nullptr,
        D_, D_, D_, D_, (long)S_ * D_, MM, (long)S_ * D_);
}

// Round 4
// 535.286 us; speedup vs baseline: 4.0654x; 1.3311x over previous
//
#include <hip/hip_runtime.h>
#include <hip/hip_bf16.h>

// B=8, S=4096, D=1024, H=16, DH=64.
// Pipeline:
//   prepack: x -> xth,xtl [B][D][S] bf16 hi/lo (in d_out), Wq -> hi/lo, Wo -> hi
//   G  = Xt Xt^T  split bf16x2, lower-triangle, SPLIT-K=4 -> fp32 partials P
//   reduce_mirror: P -> Gh/Gl bf16 (full symmetric matrix)
//   x -> xh bf16 (after P dead; aliases P region)
//   Mt = G @ Wq^T (split)        -> Mt fp32 (aliases P region)
//   scores/softmax (fp32)        -> att
//   T build (fp32)               -> Th bf16 (aliases Gh)
//   Et = Wo x T-rows (bf16)      -> Eth (aliases Gl)
//   out = x @ E (bf16)           -> out fp32

#define B_ 8
#define S_ 4096
#define D_ 1024
#define H_ 16

typedef unsigned short u16;
typedef __attribute__((ext_vector_type(4))) short short4v;
typedef __attribute__((ext_vector_type(8))) short short8v;
typedef __attribute__((ext_vector_type(4))) float f32x4;

typedef __attribute__((address_space(3))) unsigned lds_u32_t;
typedef const __attribute__((address_space(1))) unsigned glb_u32_t;

__device__ __forceinline__ unsigned short f2bf(float f) {
    unsigned u = __builtin_bit_cast(unsigned, f);
    u += 0x7FFFu + ((u >> 16) & 1u);
    return (unsigned short)(u >> 16);
}
__device__ __forceinline__ float bf2f(unsigned short s) {
    unsigned u = (unsigned)s << 16;
    return __builtin_bit_cast(float, u);
}
__device__ __forceinline__ void gll16(const u16* g, u16* lds) {
    __builtin_amdgcn_global_load_lds((glb_u32_t*)g, (lds_u32_t*)lds, 16, 0, 0);
}
__device__ __forceinline__ void pair_decode(int pair, int& ti, int& tj) {
    ti = (int)((sqrtf(8.f * pair + 1.f) - 1.f) * 0.5f);
    if ((ti + 1) * (ti + 2) / 2 <= pair) ++ti;
    if (ti * (ti + 1) / 2 > pair) --ti;
    tj = pair - ti * (ti + 1) / 2;
}

// ---------------- Gram split-K kernel ----------------
// 1152 blocks: 36 lower-tri pairs x 4 K-chunks x 8 batches, XCD-grouped by batch.
// Each block: 128x128 tile over its K=1024 chunk, split bf16x2 (hh+hl+lh),
// writes fp32 partial tile to P[(chunk*8+batch)*36+pair].
__global__ __launch_bounds__(256) void gram_splitk(
    const u16* __restrict__ xth, const u16* __restrict__ xtl, float* __restrict__ P)
{
    __shared__ u16 As[2 * 128 * 32];
    __shared__ u16 Bs[2 * 128 * 32];

    const int l = ((blockIdx.x & 7) * 144) + (blockIdx.x >> 3);
    const int batch = l / 144;
    const int rem = l - batch * 144;
    const int chunk = rem / 36;
    const int pair = rem - chunk * 36;
    int ti, tj;
    pair_decode(pair, ti, tj);

    const int t = threadIdx.x, lane = t & 63, wave = t >> 6;
    const int wm = (wave >> 1) * 64, wn = (wave & 1) * 64;
    const int fr = lane & 15, kg = lane >> 4;

    const u16* Agh = xth + ((long)batch * D_ + ti * 128) * S_ + chunk * 1024;
    const u16* Bgh = xth + ((long)batch * D_ + tj * 128) * S_ + chunk * 1024;
    const u16* Agl = xtl + ((long)batch * D_ + ti * 128) * S_ + chunk * 1024;
    const u16* Bgl = xtl + ((long)batch * D_ + tj * 128) * S_ + chunk * 1024;

    f32x4 acc[4][4];
#pragma unroll
    for (int i = 0; i < 4; ++i)
#pragma unroll
        for (int j = 0; j < 4; ++j) acc[i][j] = (f32x4){0.f, 0.f, 0.f, 0.f};

    for (int k0 = 0; k0 < 1024; k0 += 32) {
        if (k0) __syncthreads();
#pragma unroll
        for (int r = 0; r < 2; ++r) {
            const int off = r * 2048 + t * 8;
            const int row = off >> 5, kc = off & 31;
            gll16(Agh + (long)row * S_ + k0 + kc, As + off);
            gll16(Bgh + (long)row * S_ + k0 + kc, Bs + off);
            gll16(Agl + (long)row * S_ + k0 + kc, As + 4096 + off);
            gll16(Bgl + (long)row * S_ + k0 + kc, Bs + 4096 + off);
        }
        __syncthreads();

        const int ao = (wm + fr) * 32 + kg * 8;
        const int bo = (wn + fr) * 32 + kg * 8;
        short8v a[4], b[4];
#pragma unroll
        for (int mt = 0; mt < 4; ++mt) a[mt] = *(const short8v*)&As[ao + mt * 512];
#pragma unroll
        for (int nt = 0; nt < 4; ++nt) b[nt] = *(const short8v*)&Bs[bo + nt * 512];
#pragma unroll
        for (int mt = 0; mt < 4; ++mt)
#pragma unroll
            for (int nt = 0; nt < 4; ++nt)
                acc[mt][nt] = __builtin_amdgcn_mfma_f32_16x16x32_bf16(a[mt], b[nt], acc[mt][nt], 0, 0, 0);
        {
            short8v bl[4];
#pragma unroll
            for (int nt = 0; nt < 4; ++nt) bl[nt] = *(const short8v*)&Bs[4096 + bo + nt * 512];
#pragma unroll
            for (int mt = 0; mt < 4; ++mt)
#pragma unroll
                for (int nt = 0; nt < 4; ++nt)
                    acc[mt][nt] = __builtin_amdgcn_mfma_f32_16x16x32_bf16(a[mt], bl[nt], acc[mt][nt], 0, 0, 0);
#pragma unroll
            for (int mt = 0; mt < 4; ++mt) a[mt] = *(const short8v*)&As[4096 + ao + mt * 512];
#pragma unroll
            for (int mt = 0; mt < 4; ++mt)
#pragma unroll
                for (int nt = 0; nt < 4; ++nt)
                    acc[mt][nt] = __builtin_amdgcn_mfma_f32_16x16x32_bf16(a[mt], b[nt], acc[mt][nt], 0, 0, 0);
        }
    }

    float* out = P + (((long)chunk * B_ + batch) * 36 + pair) * 16384;
#pragma unroll
    for (int mt = 0; mt < 4; ++mt)
#pragma unroll
        for (int nt = 0; nt < 4; ++nt)
#pragma unroll
            for (int q = 0; q < 4; ++q)
                out[(wm + mt * 16 + kg * 4 + q) * 128 + wn + nt * 16 + fr] = acc[mt][nt][q];
}

// ---------------- reduce partials + convert + mirror ----------------
// grid (36, 8). Sums 4 chunks of a tile, writes bf16 hi/lo at (ti,tj) and
// transpose-mirrored at (tj,ti).
__global__ __launch_bounds__(256) void reduce_mirror(
    const float* __restrict__ P, u16* __restrict__ Gh, u16* __restrict__ Gl)
{
    __shared__ u16 th[128][132];
    __shared__ u16 tl[128][132];
    const int pair = blockIdx.x, b = blockIdx.y;
    int ti, tj;
    pair_decode(pair, ti, tj);
    const int t = threadIdx.x;
    const long tile = 16384;
    const long cs = (long)B_ * 36 * tile;
    const float* base = P + ((long)b * 36 + pair) * tile;
    u16* GhB = Gh + (long)b * D_ * D_;
    u16* GlB = Gl + (long)b * D_ * D_;

#pragma unroll
    for (int e = 0; e < 16; ++e) {
        const int idx = e * 1024 + t * 4;
        float4 s0 = *(const float4*)&base[idx];
        float4 s1 = *(const float4*)&base[cs + idx];
        float4 s2 = *(const float4*)&base[2 * cs + idx];
        float4 s3 = *(const float4*)&base[3 * cs + idx];
        float f[4] = {s0.x + s1.x + s2.x + s3.x, s0.y + s1.y + s2.y + s3.y,
                      s0.z + s1.z + s2.z + s3.z, s0.w + s1.w + s2.w + s3.w};
        const int r = idx >> 7, c = idx & 127;
        short4v hv, lv;
#pragma unroll
        for (int j = 0; j < 4; ++j) {
            const unsigned short h = f2bf(f[j]);
            hv[j] = (short)h;
            lv[j] = (short)f2bf(f[j] - bf2f(h));
        }
        *(short4v*)&GhB[(long)(ti * 128 + r) * D_ + tj * 128 + c] = hv;
        *(short4v*)&GlB[(long)(ti * 128 + r) * D_ + tj * 128 + c] = lv;
        if (ti != tj) {
#pragma unroll
            for (int j = 0; j < 4; ++j) {
                th[c + j][r] = hv[j];
                tl[c + j][r] = lv[j];
            }
        }
    }
    if (ti != tj) {
        __syncthreads();
#pragma unroll
        for (int e = 0; e < 16; ++e) {
            const int idx = e * 1024 + t * 4;
            const int r = idx >> 7, c = idx & 127;
            short4v hv = *(const short4v*)&th[r][c];
            short4v lv = *(const short4v*)&tl[r][c];
            *(short4v*)&GhB[(long)(tj * 128 + r) * D_ + ti * 128 + c] = hv;
            *(short4v*)&GlB[(long)(tj * 128 + r) * D_ + ti * 128 + c] = lv;
        }
    }
}

// ---------------- unified MFMA GEMM (m97 structure) ----------------
// C[m][n] = sum_k A[m][k]*B[n][k], row-major bf16 operands.
// OUT: 0 = fp32, 1 = bf16 hi.  SPLIT: + A_hi*B_lo + A_lo*B_hi.
template<int OUT, bool SPLIT>
__global__ __launch_bounds__(256) void gemm_bf16(
    const u16* __restrict__ Ah, const u16* __restrict__ Al,
    const u16* __restrict__ Bh, const u16* __restrict__ Bl,
    float* __restrict__ Cf, u16* __restrict__ Ch,
    int K, int lda, int ldb, int ldc, long sA, long sB, long sC)
{
    __shared__ u16 As[(SPLIT ? 2 : 1) * 128 * 32];
    __shared__ u16 Bs[(SPLIT ? 2 : 1) * 128 * 32];

    const int bn0 = blockIdx.x * 128, bm0 = blockIdx.y * 128;
    const int t = threadIdx.x, lane = t & 63, wave = t >> 6;
    const int wm = (wave >> 1) * 64, wn = (wave & 1) * 64;
    const int fr = lane & 15, kg = lane >> 4;

    const u16* Agh = Ah + (long)blockIdx.z * sA + (long)bm0 * lda;
    const u16* Bgh = Bh + (long)blockIdx.z * sB + (long)bn0 * ldb;
    const u16* Agl = SPLIT ? (Al + (long)blockIdx.z * sA + (long)bm0 * lda) : nullptr;
    const u16* Bgl = SPLIT ? (Bl + (long)blockIdx.z * sB + (long)bn0 * ldb) : nullptr;

    f32x4 acc[4][4];
#pragma unroll
    for (int i = 0; i < 4; ++i)
#pragma unroll
        for (int j = 0; j < 4; ++j) acc[i][j] = (f32x4){0.f, 0.f, 0.f, 0.f};

    for (int k0 = 0; k0 < K; k0 += 32) {
        if (k0) __syncthreads();
#pragma unroll
        for (int r = 0; r < 2; ++r) {
            const int off = r * 2048 + t * 8;
            const int row = off >> 5, kc = off & 31;
            gll16(Agh + (long)row * lda + k0 + kc, As + off);
            gll16(Bgh + (long)row * ldb + k0 + kc, Bs + off);
            if (SPLIT) {
                gll16(Agl + (long)row * lda + k0 + kc, As + 4096 + off);
                gll16(Bgl + (long)row * ldb + k0 + kc, Bs + 4096 + off);
            }
        }
        __syncthreads();

        const int ao = (wm + fr) * 32 + kg * 8;
        const int bo = (wn + fr) * 32 + kg * 8;
        short8v a[4], b[4];
#pragma unroll
        for (int mt = 0; mt < 4; ++mt) a[mt] = *(const short8v*)&As[ao + mt * 512];
#pragma unroll
        for (int nt = 0; nt < 4; ++nt) b[nt] = *(const short8v*)&Bs[bo + nt * 512];
#pragma unroll
        for (int mt = 0; mt < 4; ++mt)
#pragma unroll
            for (int nt = 0; nt < 4; ++nt)
                acc[mt][nt] = __builtin_amdgcn_mfma_f32_16x16x32_bf16(a[mt], b[nt], acc[mt][nt], 0, 0, 0);
        if (SPLIT) {
            short8v bl[4];
#pragma unroll
            for (int nt = 0; nt < 4; ++nt) bl[nt] = *(const short8v*)&Bs[4096 + bo + nt * 512];
#pragma unroll
            for (int mt = 0; mt < 4; ++mt)
#pragma unroll
                for (int nt = 0; nt < 4; ++nt)
                    acc[mt][nt] = __builtin_amdgcn_mfma_f32_16x16x32_bf16(a[mt], bl[nt], acc[mt][nt], 0, 0, 0);
#pragma unroll
            for (int mt = 0; mt < 4; ++mt) a[mt] = *(const short8v*)&As[4096 + ao + mt * 512];
#pragma unroll
            for (int mt = 0; mt < 4; ++mt)
#pragma unroll
                for (int nt = 0; nt < 4; ++nt)
                    acc[mt][nt] = __builtin_amdgcn_mfma_f32_16x16x32_bf16(a[mt], b[nt], acc[mt][nt], 0, 0, 0);
        }
    }

#pragma unroll
    for (int mt = 0; mt < 4; ++mt)
#pragma unroll
        for (int nt = 0; nt < 4; ++nt)
#pragma unroll
            for (int q = 0; q < 4; ++q) {
                const int row = bm0 + wm + mt * 16 + kg * 4 + q;
                const int col = bn0 + wn + nt * 16 + fr;
                const float v = acc[mt][nt][q];
                const long idx = (long)blockIdx.z * sC + (long)row * ldc + col;
                if (OUT == 0) Cf[idx] = v;
                else Ch[idx] = f2bf(v);
            }
}

// ---------------- prepack: x -> transposed bf16 hi/lo ----------------
__global__ __launch_bounds__(256) void prepack_xt(
    const float* __restrict__ x, u16* __restrict__ xth, u16* __restrict__ xtl)
{
    __shared__ float tile[64][65];
    const int d0 = blockIdx.x * 64, s0 = blockIdx.y * 64, b = blockIdx.z;
    const float* xb = x + (long)b * S_ * D_;
    const int t = threadIdx.x;
    const int sr = t >> 4, dc = (t & 15) * 4;
#pragma unroll
    for (int r = 0; r < 4; ++r) {
        const int s = sr + r * 16;
        float4 v = *(const float4*)&xb[(long)(s0 + s) * D_ + d0 + dc];
        tile[dc + 0][s] = v.x;
        tile[dc + 1][s] = v.y;
        tile[dc + 2][s] = v.z;
        tile[dc + 3][s] = v.w;
    }
    __syncthreads();
    const int dr = t >> 4, sc = (t & 15) * 4;
    u16* th = xth + (long)b * D_ * S_;
    u16* tl = xtl + (long)b * D_ * S_;
#pragma unroll
    for (int r = 0; r < 4; ++r) {
        const int d = dr + r * 16;
        short4v hv, lv;
#pragma unroll
        for (int j = 0; j < 4; ++j) {
            const float v = tile[d][sc + j];
            const unsigned short h = f2bf(v);
            hv[j] = (short)h;
            lv[j] = (short)f2bf(v - bf2f(h));
        }
        *(short4v*)&th[(long)(d0 + d) * S_ + s0 + sc] = hv;
        *(short4v*)&tl[(long)(d0 + d) * S_ + s0 + sc] = lv;
    }
}

// ---------------- generic fp32 -> bf16 convert ----------------
template<bool SP>
__global__ __launch_bounds__(256) void convert_bf16(
    const float* __restrict__ in, u16* __restrict__ h, u16* __restrict__ l, long n)
{
    const long i = ((long)blockIdx.x * 256 + threadIdx.x) * 4;
    if (i >= n) return;
    float4 v = *(const float4*)&in[i];
    float f[4] = {v.x, v.y, v.z, v.w};
    short4v hv, lv;
#pragma unroll
    for (int j = 0; j < 4; ++j) {
        const unsigned short hh = f2bf(f[j]);
        hv[j] = (short)hh;
        lv[j] = (short)f2bf(f[j] - bf2f(hh));
    }
    *(short4v*)&h[i] = hv;
    if (SP) *(short4v*)&l[i] = lv;
}

// ---------------- scores + softmax (fp32) ----------------
__global__ __launch_bounds__(256) void scores_softmax(
    const float* __restrict__ Mt, const float* __restrict__ Wk, float* __restrict__ att)
{
    __shared__ float Ms2[64][65];
    __shared__ float Ks[64][65];
    __shared__ float Sm[64][65];
    __shared__ float rowm[64], rows[64];
    const int bh = blockIdx.x;
    const int b = bh >> 4, h = bh & 15;
    const float* Mbase = Mt + (long)b * D_ * D_ + h * 64;
    const float* Kbase = Wk + (long)h * 64 * D_;
    const int t = threadIdx.x;
    const int e = t & 63, dg = t >> 6;

    float acc[16];
#pragma unroll
    for (int i = 0; i < 16; ++i) acc[i] = 0.f;

    for (int jc = 0; jc < D_; jc += 64) {
        __syncthreads();
        {
            int row = t >> 2, c4 = (t & 3) * 16;
#pragma unroll
            for (int r = 0; r < 4; ++r) {
                float4 v = *(const float4*)&Mbase[(long)(jc + row) * D_ + c4 + r * 4];
                Ms2[row][c4 + r * 4 + 0] = v.x;
                Ms2[row][c4 + r * 4 + 1] = v.y;
                Ms2[row][c4 + r * 4 + 2] = v.z;
                Ms2[row][c4 + r * 4 + 3] = v.w;
                float4 w = *(const float4*)&Kbase[(long)row * D_ + jc + c4 + r * 4];
                Ks[row][c4 + r * 4 + 0] = w.x;
                Ks[row][c4 + r * 4 + 1] = w.y;
                Ks[row][c4 + r * 4 + 2] = w.z;
                Ks[row][c4 + r * 4 + 3] = w.w;
            }
        }
        __syncthreads();
#pragma unroll 8
        for (int jj = 0; jj < 64; ++jj) {
            float kv = Ks[e][jj];
#pragma unroll
            for (int dd = 0; dd < 16; ++dd)
                acc[dd] = fmaf(Ms2[jj][dg * 16 + dd], kv, acc[dd]);
        }
    }
    __syncthreads();
#pragma unroll
    for (int dd = 0; dd < 16; ++dd) Sm[dg * 16 + dd][e] = acc[dd] * 0.125f;
    __syncthreads();
    if (t < 64) {
        float m = -1e30f;
        for (int ee = 0; ee < 64; ++ee) m = fmaxf(m, Sm[t][ee]);
        float s = 0.f;
        for (int ee = 0; ee < 64; ++ee) s += expf(Sm[t][ee] - m);
        rowm[t] = m;
        rows[t] = 1.0f / s;
    }
    __syncthreads();
    float* abase = att + (long)bh * 64 * 64;
#pragma unroll
    for (int dd = 0; dd < 16; ++dd) {
        int d = dg * 16 + dd;
        abase[d * 64 + e] = expf(Sm[d][e] - rowm[d]) * rows[d];
    }
}

// ---------------- T build (fp32 compute, bf16 out) ----------------
__global__ __launch_bounds__(256) void build_T(
    const float* __restrict__ Wv, const float* __restrict__ att, u16* __restrict__ T)
{
    __shared__ float atts[64][65];
    __shared__ float Wvs[64][65];
    const int i0 = blockIdx.x * 64, h = blockIdx.y, b = blockIdx.z;
    const int t = threadIdx.x;
    {
        int row = t >> 2, c4 = (t & 3) * 16;
        const float* ab = att + (((long)b * H_ + h) * 64) * 64;
        const float* wb = Wv + (long)h * 64 * D_ + i0;
#pragma unroll
        for (int r = 0; r < 4; ++r) {
            float4 v = *(const float4*)&ab[row * 64 + c4 + r * 4];
            atts[row][c4 + r * 4 + 0] = v.x;
            atts[row][c4 + r * 4 + 1] = v.y;
            atts[row][c4 + r * 4 + 2] = v.z;
            atts[row][c4 + r * 4 + 3] = v.w;
            float4 w = *(const float4*)&wb[(long)row * D_ + c4 + r * 4];
            Wvs[row][c4 + r * 4 + 0] = w.x;
            Wvs[row][c4 + r * 4 + 1] = w.y;
            Wvs[row][c4 + r * 4 + 2] = w.z;
            Wvs[row][c4 + r * 4 + 3] = w.w;
        }
    }
    __syncthreads();
    const int e = t & 63, ig = t >> 6;
    float acc[16];
#pragma unroll
    for (int i = 0; i < 16; ++i) acc[i] = 0.f;
#pragma unroll 8
    for (int d = 0; d < 64; ++d) {
        float av = atts[d][e];
#pragma unroll
        for (int ii = 0; ii < 16; ++ii)
            acc[ii] = fmaf(Wvs[d][ig * 16 + ii], av, acc[ii]);
    }
    u16* Tb = T + (long)b * D_ * D_;
#pragma unroll
    for (int ii = 0; ii < 16; ++ii) {
        int i = i0 + ig * 16 + ii;
        Tb[(long)i * D_ + h * 64 + e] = f2bf(acc[ii]);
    }
}

extern "C" void kernel_launch(void* const* d_in, const int* in_sizes, int n_in,
                              void* d_out, int out_size, void* d_ws, size_t ws_size,
                              hipStream_t stream) {
    const float* x  = (const float*)d_in[0];
    const float* Wq = (const float*)d_in[1];
    const float* Wk = (const float*)d_in[2];
    const float* Wv = (const float*)d_in[3];
    const float* Wo = (const float*)d_in[4];
    float* out = (float*)d_out;

    const long MM = (long)D_ * D_;          // 1,048,576
    const long XE = (long)B_ * S_ * D_;     // 33,554,432
    const long GE = (long)B_ * MM;          // 8,388,608

    // xth/xtl live in d_out (2*XE u16 = exactly out bytes); dead before final GEMM.
    u16* xth = (u16*)d_out;
    u16* xtl = xth + XE;

    // ws region R0 (100.7 MB): P (75.5 MB) during Gram phase; xh+Mt afterwards.
    char* w = (char*)d_ws;
    float* P  = (float*)w;                  // 4*8*36*16384*4 = 75.5 MB
    u16* xh   = (u16*)w;                    // 67.1 MB   (after P dead)
    float* Mt = (float*)(w + XE * 2);       // 33.6 MB
    w += XE * 2 + GE * 4;
    u16* Gh   = (u16*)w;  w += GE * 2;      // 16.8 MB (later Th)
    u16* Gl   = (u16*)w;  w += GE * 2;      // 16.8 MB (later Eth)
    float* att = (float*)w; w += (long)B_ * H_ * 64 * 64 * 4;  // 2.1 MB
    u16* Wqh  = (u16*)w;  w += MM * 2;
    u16* Wql  = (u16*)w;  w += MM * 2;
    u16* Woh  = (u16*)w;  w += MM * 2;
    u16* Th  = Gh;
    u16* Eth = Gl;

    // 1. prepacks
    prepack_xt<<<dim3(D_ / 64, S_ / 64, B_), 256, 0, stream>>>(x, xth, xtl);
    convert_bf16<true ><<<MM / 1024, 256, 0, stream>>>(Wq, Wqh, Wql, MM);
    convert_bf16<false><<<MM / 1024, 256, 0, stream>>>(Wo, Woh, nullptr, MM);

    // 2. Gram split-K -> P
    gram_splitk<<<36 * 4 * B_, 256, 0, stream>>>(xth, xtl, P);

    // 3. reduce + mirror -> Gh/Gl
    reduce_mirror<<<dim3(36, B_), 256, 0, stream>>>(P, Gh, Gl);

    // 4. xh (P now dead)
    convert_bf16<false><<<XE / 1024, 256, 0, stream>>>(x, xh, nullptr, XE);

    // 5. Mt[i][j] = sum_k G[i][k] Wq[j][k]  (split) -> fp32
    gemm_bf16<0, true><<<dim3(8, 8, B_), 256, 0, stream>>>(
        Gh, Gl, Wqh, Wql, Mt, nullptr,
        D_, D_, D_, D_, MM, 0, MM);

    // 6. scores + softmax
    scores_softmax<<<B_ * H_, 256, 0, stream>>>(Mt, Wk, att);

    // 7. T (bf16) -> Th (aliases Gh; G consumed)
    build_T<<<dim3(D_ / 64, H_, B_), 256, 0, stream>>>(Wv, att, Th);

    // 8. Et[j][i] = sum_k Wo[j][k] T[i][k] -> bf16 (aliases Gl)
    gemm_bf16<1, false><<<dim3(8, 8, B_), 256, 0, stream>>>(
        Woh, nullptr, Th, nullptr, nullptr, Eth,
        D_, D_, D_, D_, 0, MM, MM);

    // 9. out[s][j] = sum_i x[s][i] Et[j][i]
    gemm_bf16<0, false><<<dim3(8, 32, B_), 256, 0, stream>>>(
        xh, nullptr, Eth, nullptr, out, nullptr,
        D_, D_, D_, D_, (long)S_ * D_, MM, (long)S_ * D_);
}

// Round 5
// 510.486 us; speedup vs baseline: 4.2629x; 1.0486x over previous
//
#include <hip/hip_runtime.h>
#include <hip/hip_bf16.h>

// B=8, S=4096, D=1024, H=16, DH=64.
// Pipeline:
//   prepack: x -> xth,xtl [B][D][S] bf16 hi/lo (in d_out), Wq -> hi/lo, Wo -> hi
//   G  = Xt Xt^T  split bf16x2, lower-triangle, SPLIT-K=4 -> fp32 partials P
//   reduce_mirror: P -> Gh/Gl bf16 (full symmetric matrix)
//   x -> xh bf16 (after P dead; aliases P region)
//   Mt = G @ Wq^T (split)        -> Mt fp32 (aliases P region)
//   scores/softmax (fp32)        -> att
//   T build (fp32)               -> Th bf16 (aliases Gh)
//   Et = Wo x T-rows (bf16)      -> Eth (aliases Gl)
//   out = x @ E (bf16)           -> out fp32   [NEW: 256^2 dbuf 2-phase + T2 swizzle]

#define B_ 8
#define S_ 4096
#define D_ 1024
#define H_ 16

typedef unsigned short u16;
typedef __attribute__((ext_vector_type(4))) short short4v;
typedef __attribute__((ext_vector_type(8))) short short8v;
typedef __attribute__((ext_vector_type(4))) float f32x4;

typedef __attribute__((address_space(3))) unsigned lds_u32_t;
typedef const __attribute__((address_space(1))) unsigned glb_u32_t;

__device__ __forceinline__ unsigned short f2bf(float f) {
    unsigned u = __builtin_bit_cast(unsigned, f);
    u += 0x7FFFu + ((u >> 16) & 1u);
    return (unsigned short)(u >> 16);
}
__device__ __forceinline__ float bf2f(unsigned short s) {
    unsigned u = (unsigned)s << 16;
    return __builtin_bit_cast(float, u);
}
__device__ __forceinline__ void gll16(const u16* g, u16* lds) {
    __builtin_amdgcn_global_load_lds((glb_u32_t*)g, (lds_u32_t*)lds, 16, 0, 0);
}
__device__ __forceinline__ void pair_decode(int pair, int& ti, int& tj) {
    ti = (int)((sqrtf(8.f * pair + 1.f) - 1.f) * 0.5f);
    if ((ti + 1) * (ti + 2) / 2 <= pair) ++ti;
    if (ti * (ti + 1) / 2 > pair) --ti;
    tj = pair - ti * (ti + 1) / 2;
}

// ---------------- 256^2 double-buffered 2-phase GEMM (final) ----------------
// C[m][n] = sum_k A[m][k]*B[n][k], row-major bf16, fp32 out.
// BM=BN=256, BK=64, 512 thr = 8 waves (2x4), per-wave 128x64 output.
// LDS 128 KiB: 2 bufs x (A 256x64 + B 256x64). st_16x32 XOR swizzle (T2):
// linear gll16 dest + inverse-swizzled global source k + swizzled read.
// One __syncthreads per K-tile (implicit vmcnt(0) drain doubles as the wait);
// stage of tile t+1 issued BEFORE compute of tile t -> latency hidden.
__global__ __launch_bounds__(512) void gemm256_bf16(
    const u16* __restrict__ A, const u16* __restrict__ B, float* __restrict__ C,
    int K, int lda, int ldb, int ldc, long sA, long sB, long sC)
{
    __shared__ u16 lds[2][2][256 * 64];

    // XCD swizzle: phys -> logical so each XCD owns one batch's 64 blocks.
    const int p = blockIdx.x;
    const int l = (p & 7) * 64 + (p >> 3);
    const int bz = l >> 6;                 // batch
    const int bm0 = ((l >> 2) & 15) * 256; // m-tile
    const int bn0 = (l & 3) * 256;         // n-tile

    const int t = threadIdx.x, lane = t & 63, wave = t >> 6;
    const int wm = (wave >> 2) * 128, wn = (wave & 3) * 64;
    const int fr = lane & 15, kg = lane >> 4;
    const int xr = ((fr >> 2) & 1) << 4;   // read-side swizzle (per-lane const)

    const u16* Ag = A + (long)bz * sA + (long)bm0 * lda;
    const u16* Bg = B + (long)bz * sB + (long)bn0 * ldb;

    f32x4 acc[8][4];
#pragma unroll
    for (int i = 0; i < 8; ++i)
#pragma unroll
        for (int j = 0; j < 4; ++j) acc[i][j] = (f32x4){0.f, 0.f, 0.f, 0.f};

    const int NT = K >> 6;

    // stage tile `tt` into buffer `bsel`
    auto stage = [&](int tt, int bsel) {
#pragma unroll
        for (int r = 0; r < 4; ++r) {
            const int idx = t + r * 512;          // 0..2047
            const int row = idx >> 3;             // 0..255
            const int kc = (idx & 7) << 3;        // 0..56 shorts
            const int ks = kc ^ (((row >> 2) & 1) << 4);  // inverse swizzle on src
            const int o = idx * 8;                // linear LDS shorts
            gll16(Ag + (long)row * lda + (tt << 6) + ks, &lds[bsel][0][o]);
            gll16(Bg + (long)row * ldb + (tt << 6) + ks, &lds[bsel][1][o]);
        }
    };

    stage(0, 0);
    __syncthreads();

    for (int tt = 0; tt < NT; ++tt) {
        const int cur = tt & 1;
        if (tt + 1 < NT) stage(tt + 1, cur ^ 1);

        const u16* As = &lds[cur][0][0];
        const u16* Bs = &lds[cur][1][0];
#pragma unroll
        for (int kh = 0; kh < 2; ++kh) {
            const int ko = (kh * 32 + kg * 8) ^ xr;
            short8v bf[4];
#pragma unroll
            for (int nt = 0; nt < 4; ++nt)
                bf[nt] = *(const short8v*)&Bs[(wn + nt * 16 + fr) * 64 + ko];
#pragma unroll
            for (int mt = 0; mt < 8; ++mt) {
                short8v af = *(const short8v*)&As[(wm + mt * 16 + fr) * 64 + ko];
#pragma unroll
                for (int nt = 0; nt < 4; ++nt)
                    acc[mt][nt] = __builtin_amdgcn_mfma_f32_16x16x32_bf16(af, bf[nt], acc[mt][nt], 0, 0, 0);
            }
        }
        __syncthreads();   // implicit vmcnt(0)+lgkmcnt(0): tile tt+1 resident, reads done
    }

    // C/D layout (m89-verified): col = lane&15, row = (lane>>4)*4 + q
#pragma unroll
    for (int mt = 0; mt < 8; ++mt)
#pragma unroll
        for (int nt = 0; nt < 4; ++nt)
#pragma unroll
            for (int q = 0; q < 4; ++q) {
                const int row = bm0 + wm + mt * 16 + kg * 4 + q;
                const int col = bn0 + wn + nt * 16 + fr;
                C[(long)bz * sC + (long)row * ldc + col] = acc[mt][nt][q];
            }
}

// ---------------- Gram split-K kernel ----------------
__global__ __launch_bounds__(256) void gram_splitk(
    const u16* __restrict__ xth, const u16* __restrict__ xtl, float* __restrict__ P)
{
    __shared__ u16 As[2 * 128 * 32];
    __shared__ u16 Bs[2 * 128 * 32];

    const int l = ((blockIdx.x & 7) * 144) + (blockIdx.x >> 3);
    const int batch = l / 144;
    const int rem = l - batch * 144;
    const int chunk = rem / 36;
    const int pair = rem - chunk * 36;
    int ti, tj;
    pair_decode(pair, ti, tj);

    const int t = threadIdx.x, lane = t & 63, wave = t >> 6;
    const int wm = (wave >> 1) * 64, wn = (wave & 1) * 64;
    const int fr = lane & 15, kg = lane >> 4;

    const u16* Agh = xth + ((long)batch * D_ + ti * 128) * S_ + chunk * 1024;
    const u16* Bgh = xth + ((long)batch * D_ + tj * 128) * S_ + chunk * 1024;
    const u16* Agl = xtl + ((long)batch * D_ + ti * 128) * S_ + chunk * 1024;
    const u16* Bgl = xtl + ((long)batch * D_ + tj * 128) * S_ + chunk * 1024;

    f32x4 acc[4][4];
#pragma unroll
    for (int i = 0; i < 4; ++i)
#pragma unroll
        for (int j = 0; j < 4; ++j) acc[i][j] = (f32x4){0.f, 0.f, 0.f, 0.f};

    for (int k0 = 0; k0 < 1024; k0 += 32) {
        if (k0) __syncthreads();
#pragma unroll
        for (int r = 0; r < 2; ++r) {
            const int off = r * 2048 + t * 8;
            const int row = off >> 5, kc = off & 31;
            gll16(Agh + (long)row * S_ + k0 + kc, As + off);
            gll16(Bgh + (long)row * S_ + k0 + kc, Bs + off);
            gll16(Agl + (long)row * S_ + k0 + kc, As + 4096 + off);
            gll16(Bgl + (long)row * S_ + k0 + kc, Bs + 4096 + off);
        }
        __syncthreads();

        const int ao = (wm + fr) * 32 + kg * 8;
        const int bo = (wn + fr) * 32 + kg * 8;
        short8v a[4], b[4];
#pragma unroll
        for (int mt = 0; mt < 4; ++mt) a[mt] = *(const short8v*)&As[ao + mt * 512];
#pragma unroll
        for (int nt = 0; nt < 4; ++nt) b[nt] = *(const short8v*)&Bs[bo + nt * 512];
#pragma unroll
        for (int mt = 0; mt < 4; ++mt)
#pragma unroll
            for (int nt = 0; nt < 4; ++nt)
                acc[mt][nt] = __builtin_amdgcn_mfma_f32_16x16x32_bf16(a[mt], b[nt], acc[mt][nt], 0, 0, 0);
        {
            short8v bl[4];
#pragma unroll
            for (int nt = 0; nt < 4; ++nt) bl[nt] = *(const short8v*)&Bs[4096 + bo + nt * 512];
#pragma unroll
            for (int mt = 0; mt < 4; ++mt)
#pragma unroll
                for (int nt = 0; nt < 4; ++nt)
                    acc[mt][nt] = __builtin_amdgcn_mfma_f32_16x16x32_bf16(a[mt], bl[nt], acc[mt][nt], 0, 0, 0);
#pragma unroll
            for (int mt = 0; mt < 4; ++mt) a[mt] = *(const short8v*)&As[4096 + ao + mt * 512];
#pragma unroll
            for (int mt = 0; mt < 4; ++mt)
#pragma unroll
                for (int nt = 0; nt < 4; ++nt)
                    acc[mt][nt] = __builtin_amdgcn_mfma_f32_16x16x32_bf16(a[mt], b[nt], acc[mt][nt], 0, 0, 0);
        }
    }

    float* out = P + (((long)chunk * B_ + batch) * 36 + pair) * 16384;
#pragma unroll
    for (int mt = 0; mt < 4; ++mt)
#pragma unroll
        for (int nt = 0; nt < 4; ++nt)
#pragma unroll
            for (int q = 0; q < 4; ++q)
                out[(wm + mt * 16 + kg * 4 + q) * 128 + wn + nt * 16 + fr] = acc[mt][nt][q];
}

// ---------------- reduce partials + convert + mirror ----------------
__global__ __launch_bounds__(256) void reduce_mirror(
    const float* __restrict__ P, u16* __restrict__ Gh, u16* __restrict__ Gl)
{
    __shared__ u16 th[128][132];
    __shared__ u16 tl[128][132];
    const int pair = blockIdx.x, b = blockIdx.y;
    int ti, tj;
    pair_decode(pair, ti, tj);
    const int t = threadIdx.x;
    const long tile = 16384;
    const long cs = (long)B_ * 36 * tile;
    const float* base = P + ((long)b * 36 + pair) * tile;
    u16* GhB = Gh + (long)b * D_ * D_;
    u16* GlB = Gl + (long)b * D_ * D_;

#pragma unroll
    for (int e = 0; e < 16; ++e) {
        const int idx = e * 1024 + t * 4;
        float4 s0 = *(const float4*)&base[idx];
        float4 s1 = *(const float4*)&base[cs + idx];
        float4 s2 = *(const float4*)&base[2 * cs + idx];
        float4 s3 = *(const float4*)&base[3 * cs + idx];
        float f[4] = {s0.x + s1.x + s2.x + s3.x, s0.y + s1.y + s2.y + s3.y,
                      s0.z + s1.z + s2.z + s3.z, s0.w + s1.w + s2.w + s3.w};
        const int r = idx >> 7, c = idx & 127;
        short4v hv, lv;
#pragma unroll
        for (int j = 0; j < 4; ++j) {
            const unsigned short h = f2bf(f[j]);
            hv[j] = (short)h;
            lv[j] = (short)f2bf(f[j] - bf2f(h));
        }
        *(short4v*)&GhB[(long)(ti * 128 + r) * D_ + tj * 128 + c] = hv;
        *(short4v*)&GlB[(long)(ti * 128 + r) * D_ + tj * 128 + c] = lv;
        if (ti != tj) {
#pragma unroll
            for (int j = 0; j < 4; ++j) {
                th[c + j][r] = hv[j];
                tl[c + j][r] = lv[j];
            }
        }
    }
    if (ti != tj) {
        __syncthreads();
#pragma unroll
        for (int e = 0; e < 16; ++e) {
            const int idx = e * 1024 + t * 4;
            const int r = idx >> 7, c = idx & 127;
            short4v hv = *(const short4v*)&th[r][c];
            short4v lv = *(const short4v*)&tl[r][c];
            *(short4v*)&GhB[(long)(tj * 128 + r) * D_ + ti * 128 + c] = hv;
            *(short4v*)&GlB[(long)(tj * 128 + r) * D_ + ti * 128 + c] = lv;
        }
    }
}

// ---------------- 128^2 MFMA GEMM (m97 structure) ----------------
template<int OUT, bool SPLIT>
__global__ __launch_bounds__(256) void gemm_bf16(
    const u16* __restrict__ Ah, const u16* __restrict__ Al,
    const u16* __restrict__ Bh, const u16* __restrict__ Bl,
    float* __restrict__ Cf, u16* __restrict__ Ch,
    int K, int lda, int ldb, int ldc, long sA, long sB, long sC)
{
    __shared__ u16 As[(SPLIT ? 2 : 1) * 128 * 32];
    __shared__ u16 Bs[(SPLIT ? 2 : 1) * 128 * 32];

    const int bn0 = blockIdx.x * 128, bm0 = blockIdx.y * 128;
    const int t = threadIdx.x, lane = t & 63, wave = t >> 6;
    const int wm = (wave >> 1) * 64, wn = (wave & 1) * 64;
    const int fr = lane & 15, kg = lane >> 4;

    const u16* Agh = Ah + (long)blockIdx.z * sA + (long)bm0 * lda;
    const u16* Bgh = Bh + (long)blockIdx.z * sB + (long)bn0 * ldb;
    const u16* Agl = SPLIT ? (Al + (long)blockIdx.z * sA + (long)bm0 * lda) : nullptr;
    const u16* Bgl = SPLIT ? (Bl + (long)blockIdx.z * sB + (long)bn0 * ldb) : nullptr;

    f32x4 acc[4][4];
#pragma unroll
    for (int i = 0; i < 4; ++i)
#pragma unroll
        for (int j = 0; j < 4; ++j) acc[i][j] = (f32x4){0.f, 0.f, 0.f, 0.f};

    for (int k0 = 0; k0 < K; k0 += 32) {
        if (k0) __syncthreads();
#pragma unroll
        for (int r = 0; r < 2; ++r) {
            const int off = r * 2048 + t * 8;
            const int row = off >> 5, kc = off & 31;
            gll16(Agh + (long)row * lda + k0 + kc, As + off);
            gll16(Bgh + (long)row * ldb + k0 + kc, Bs + off);
            if (SPLIT) {
                gll16(Agl + (long)row * lda + k0 + kc, As + 4096 + off);
                gll16(Bgl + (long)row * ldb + k0 + kc, Bs + 4096 + off);
            }
        }
        __syncthreads();

        const int ao = (wm + fr) * 32 + kg * 8;
        const int bo = (wn + fr) * 32 + kg * 8;
        short8v a[4], b[4];
#pragma unroll
        for (int mt = 0; mt < 4; ++mt) a[mt] = *(const short8v*)&As[ao + mt * 512];
#pragma unroll
        for (int nt = 0; nt < 4; ++nt) b[nt] = *(const short8v*)&Bs[bo + nt * 512];
#pragma unroll
        for (int mt = 0; mt < 4; ++mt)
#pragma unroll
            for (int nt = 0; nt < 4; ++nt)
                acc[mt][nt] = __builtin_amdgcn_mfma_f32_16x16x32_bf16(a[mt], b[nt], acc[mt][nt], 0, 0, 0);
        if (SPLIT) {
            short8v bl[4];
#pragma unroll
            for (int nt = 0; nt < 4; ++nt) bl[nt] = *(const short8v*)&Bs[4096 + bo + nt * 512];
#pragma unroll
            for (int mt = 0; mt < 4; ++mt)
#pragma unroll
                for (int nt = 0; nt < 4; ++nt)
                    acc[mt][nt] = __builtin_amdgcn_mfma_f32_16x16x32_bf16(a[mt], bl[nt], acc[mt][nt], 0, 0, 0);
#pragma unroll
            for (int mt = 0; mt < 4; ++mt) a[mt] = *(const short8v*)&As[4096 + ao + mt * 512];
#pragma unroll
            for (int mt = 0; mt < 4; ++mt)
#pragma unroll
                for (int nt = 0; nt < 4; ++nt)
                    acc[mt][nt] = __builtin_amdgcn_mfma_f32_16x16x32_bf16(a[mt], b[nt], acc[mt][nt], 0, 0, 0);
        }
    }

#pragma unroll
    for (int mt = 0; mt < 4; ++mt)
#pragma unroll
        for (int nt = 0; nt < 4; ++nt)
#pragma unroll
            for (int q = 0; q < 4; ++q) {
                const int row = bm0 + wm + mt * 16 + kg * 4 + q;
                const int col = bn0 + wn + nt * 16 + fr;
                const float v = acc[mt][nt][q];
                const long idx = (long)blockIdx.z * sC + (long)row * ldc + col;
                if (OUT == 0) Cf[idx] = v;
                else Ch[idx] = f2bf(v);
            }
}

// ---------------- prepack: x -> transposed bf16 hi/lo ----------------
__global__ __launch_bounds__(256) void prepack_xt(
    const float* __restrict__ x, u16* __restrict__ xth, u16* __restrict__ xtl)
{
    __shared__ float tile[64][65];
    const int d0 = blockIdx.x * 64, s0 = blockIdx.y * 64, b = blockIdx.z;
    const float* xb = x + (long)b * S_ * D_;
    const int t = threadIdx.x;
    const int sr = t >> 4, dc = (t & 15) * 4;
#pragma unroll
    for (int r = 0; r < 4; ++r) {
        const int s = sr + r * 16;
        float4 v = *(const float4*)&xb[(long)(s0 + s) * D_ + d0 + dc];
        tile[dc + 0][s] = v.x;
        tile[dc + 1][s] = v.y;
        tile[dc + 2][s] = v.z;
        tile[dc + 3][s] = v.w;
    }
    __syncthreads();
    const int dr = t >> 4, sc = (t & 15) * 4;
    u16* th = xth + (long)b * D_ * S_;
    u16* tl = xtl + (long)b * D_ * S_;
#pragma unroll
    for (int r = 0; r < 4; ++r) {
        const int d = dr + r * 16;
        short4v hv, lv;
#pragma unroll
        for (int j = 0; j < 4; ++j) {
            const float v = tile[d][sc + j];
            const unsigned short h = f2bf(v);
            hv[j] = (short)h;
            lv[j] = (short)f2bf(v - bf2f(h));
        }
        *(short4v*)&th[(long)(d0 + d) * S_ + s0 + sc] = hv;
        *(short4v*)&tl[(long)(d0 + d) * S_ + s0 + sc] = lv;
    }
}

// ---------------- generic fp32 -> bf16 convert ----------------
template<bool SP>
__global__ __launch_bounds__(256) void convert_bf16(
    const float* __restrict__ in, u16* __restrict__ h, u16* __restrict__ l, long n)
{
    const long i = ((long)blockIdx.x * 256 + threadIdx.x) * 4;
    if (i >= n) return;
    float4 v = *(const float4*)&in[i];
    float f[4] = {v.x, v.y, v.z, v.w};
    short4v hv, lv;
#pragma unroll
    for (int j = 0; j < 4; ++j) {
        const unsigned short hh = f2bf(f[j]);
        hv[j] = (short)hh;
        lv[j] = (short)f2bf(f[j] - bf2f(hh));
    }
    *(short4v*)&h[i] = hv;
    if (SP) *(short4v*)&l[i] = lv;
}

// ---------------- scores + softmax (fp32) ----------------
__global__ __launch_bounds__(256) void scores_softmax(
    const float* __restrict__ Mt, const float* __restrict__ Wk, float* __restrict__ att)
{
    __shared__ float Ms2[64][65];
    __shared__ float Ks[64][65];
    __shared__ float Sm[64][65];
    __shared__ float rowm[64], rows[64];
    const int bh = blockIdx.x;
    const int b = bh >> 4, h = bh & 15;
    const float* Mbase = Mt + (long)b * D_ * D_ + h * 64;
    const float* Kbase = Wk + (long)h * 64 * D_;
    const int t = threadIdx.x;
    const int e = t & 63, dg = t >> 6;

    float acc[16];
#pragma unroll
    for (int i = 0; i < 16; ++i) acc[i] = 0.f;

    for (int jc = 0; jc < D_; jc += 64) {
        __syncthreads();
        {
            int row = t >> 2, c4 = (t & 3) * 16;
#pragma unroll
            for (int r = 0; r < 4; ++r) {
                float4 v = *(const float4*)&Mbase[(long)(jc + row) * D_ + c4 + r * 4];
                Ms2[row][c4 + r * 4 + 0] = v.x;
                Ms2[row][c4 + r * 4 + 1] = v.y;
                Ms2[row][c4 + r * 4 + 2] = v.z;
                Ms2[row][c4 + r * 4 + 3] = v.w;
                float4 w = *(const float4*)&Kbase[(long)row * D_ + jc + c4 + r * 4];
                Ks[row][c4 + r * 4 + 0] = w.x;
                Ks[row][c4 + r * 4 + 1] = w.y;
                Ks[row][c4 + r * 4 + 2] = w.z;
                Ks[row][c4 + r * 4 + 3] = w.w;
            }
        }
        __syncthreads();
#pragma unroll 8
        for (int jj = 0; jj < 64; ++jj) {
            float kv = Ks[e][jj];
#pragma unroll
            for (int dd = 0; dd < 16; ++dd)
                acc[dd] = fmaf(Ms2[jj][dg * 16 + dd], kv, acc[dd]);
        }
    }
    __syncthreads();
#pragma unroll
    for (int dd = 0; dd < 16; ++dd) Sm[dg * 16 + dd][e] = acc[dd] * 0.125f;
    __syncthreads();
    if (t < 64) {
        float m = -1e30f;
        for (int ee = 0; ee < 64; ++ee) m = fmaxf(m, Sm[t][ee]);
        float s = 0.f;
        for (int ee = 0; ee < 64; ++ee) s += expf(Sm[t][ee] - m);
        rowm[t] = m;
        rows[t] = 1.0f / s;
    }
    __syncthreads();
    float* abase = att + (long)bh * 64 * 64;
#pragma unroll
    for (int dd = 0; dd < 16; ++dd) {
        int d = dg * 16 + dd;
        abase[d * 64 + e] = expf(Sm[d][e] - rowm[d]) * rows[d];
    }
}

// ---------------- T build (fp32 compute, bf16 out) ----------------
__global__ __launch_bounds__(256) void build_T(
    const float* __restrict__ Wv, const float* __restrict__ att, u16* __restrict__ T)
{
    __shared__ float atts[64][65];
    __shared__ float Wvs[64][65];
    const int i0 = blockIdx.x * 64, h = blockIdx.y, b = blockIdx.z;
    const int t = threadIdx.x;
    {
        int row = t >> 2, c4 = (t & 3) * 16;
        const float* ab = att + (((long)b * H_ + h) * 64) * 64;
        const float* wb = Wv + (long)h * 64 * D_ + i0;
#pragma unroll
        for (int r = 0; r < 4; ++r) {
            float4 v = *(const float4*)&ab[row * 64 + c4 + r * 4];
            atts[row][c4 + r * 4 + 0] = v.x;
            atts[row][c4 + r * 4 + 1] = v.y;
            atts[row][c4 + r * 4 + 2] = v.z;
            atts[row][c4 + r * 4 + 3] = v.w;
            float4 w = *(const float4*)&wb[(long)row * D_ + c4 + r * 4];
            Wvs[row][c4 + r * 4 + 0] = w.x;
            Wvs[row][c4 + r * 4 + 1] = w.y;
            Wvs[row][c4 + r * 4 + 2] = w.z;
            Wvs[row][c4 + r * 4 + 3] = w.w;
        }
    }
    __syncthreads();
    const int e = t & 63, ig = t >> 6;
    float acc[16];
#pragma unroll
    for (int i = 0; i < 16; ++i) acc[i] = 0.f;
#pragma unroll 8
    for (int d = 0; d < 64; ++d) {
        float av = atts[d][e];
#pragma unroll
        for (int ii = 0; ii < 16; ++ii)
            acc[ii] = fmaf(Wvs[d][ig * 16 + ii], av, acc[ii]);
    }
    u16* Tb = T + (long)b * D_ * D_;
#pragma unroll
    for (int ii = 0; ii < 16; ++ii) {
        int i = i0 + ig * 16 + ii;
        Tb[(long)i * D_ + h * 64 + e] = f2bf(acc[ii]);
    }
}

extern "C" void kernel_launch(void* const* d_in, const int* in_sizes, int n_in,
                              void* d_out, int out_size, void* d_ws, size_t ws_size,
                              hipStream_t stream) {
    const float* x  = (const float*)d_in[0];
    const float* Wq = (const float*)d_in[1];
    const float* Wk = (const float*)d_in[2];
    const float* Wv = (const float*)d_in[3];
    const float* Wo = (const float*)d_in[4];
    float* out = (float*)d_out;

    const long MM = (long)D_ * D_;          // 1,048,576
    const long XE = (long)B_ * S_ * D_;     // 33,554,432
    const long GE = (long)B_ * MM;          // 8,388,608

    // xth/xtl live in d_out; dead before final GEMM writes out.
    u16* xth = (u16*)d_out;
    u16* xtl = xth + XE;

    // ws region R0: P (75.5 MB) during Gram; xh+Mt afterwards (disjoint lifetimes).
    char* w = (char*)d_ws;
    float* P  = (float*)w;
    u16* xh   = (u16*)w;
    float* Mt = (float*)(w + XE * 2);
    w += XE * 2 + GE * 4;
    u16* Gh   = (u16*)w;  w += GE * 2;
    u16* Gl   = (u16*)w;  w += GE * 2;
    float* att = (float*)w; w += (long)B_ * H_ * 64 * 64 * 4;
    u16* Wqh  = (u16*)w;  w += MM * 2;
    u16* Wql  = (u16*)w;  w += MM * 2;
    u16* Woh  = (u16*)w;  w += MM * 2;
    u16* Th  = Gh;
    u16* Eth = Gl;

    // 1. prepacks
    prepack_xt<<<dim3(D_ / 64, S_ / 64, B_), 256, 0, stream>>>(x, xth, xtl);
    convert_bf16<true ><<<MM / 1024, 256, 0, stream>>>(Wq, Wqh, Wql, MM);
    convert_bf16<false><<<MM / 1024, 256, 0, stream>>>(Wo, Woh, nullptr, MM);

    // 2. Gram split-K -> P
    gram_splitk<<<36 * 4 * B_, 256, 0, stream>>>(xth, xtl, P);

    // 3. reduce + mirror -> Gh/Gl
    reduce_mirror<<<dim3(36, B_), 256, 0, stream>>>(P, Gh, Gl);

    // 4. xh (P now dead)
    convert_bf16<false><<<XE / 1024, 256, 0, stream>>>(x, xh, nullptr, XE);

    // 5. Mt[i][j] = sum_k G[i][k] Wq[j][k]  (split) -> fp32
    gemm_bf16<0, true><<<dim3(8, 8, B_), 256, 0, stream>>>(
        Gh, Gl, Wqh, Wql, Mt, nullptr,
        D_, D_, D_, D_, MM, 0, MM);

    // 6. scores + softmax
    scores_softmax<<<B_ * H_, 256, 0, stream>>>(Mt, Wk, att);

    // 7. T (bf16) -> Th (aliases Gh; G consumed)
    build_T<<<dim3(D_ / 64, H_, B_), 256, 0, stream>>>(Wv, att, Th);

    // 8. Et[j][i] = sum_k Wo[j][k] T[i][k] -> bf16 (aliases Gl)
    gemm_bf16<1, false><<<dim3(8, 8, B_), 256, 0, stream>>>(
        Woh, nullptr, Th, nullptr, nullptr, Eth,
        D_, D_, D_, D_, 0, MM, MM);

    // 9. out[s][j] = sum_i x[s][i] Et[j][i]  -- 256^2 dbuf 2-phase + T2 swizzle
    gemm256_bf16<<<(S_ / 256) * (D_ / 256) * B_, 512, 0, stream>>>(
        xh, Eth, out,
        D_, D_, D_, D_, (long)S_ * D_, MM, (long)S_ * D_);
}

// Round 6
// 476.166 us; speedup vs baseline: 4.5702x; 1.0721x over previous
//
#include <hip/hip_runtime.h>
#include <hip/hip_bf16.h>

// B=8, S=4096, D=1024, H=16, DH=64.
// Pipeline:
//   prepack: x -> xth,xtl [B][D][S] bf16 hi/lo (in d_out) [+ xh fused if ws allows]
//   G  = Xt Xt^T  split bf16x2, lower-triangle, SPLIT-K=4 -> fp32 partials P
//   reduce_mirror: P -> Gh/Gl bf16
//   Mt = G @ Wq^T (split) -> fp32 ; scores/softmax ; T build ; Et = Wo x T
//   out = x @ E  [256^2, BK=32, 3-buffer counted-vmcnt pipeline (T4)]

#define B_ 8
#define S_ 4096
#define D_ 1024
#define H_ 16

typedef unsigned short u16;
typedef __attribute__((ext_vector_type(4))) short short4v;
typedef __attribute__((ext_vector_type(8))) short short8v;
typedef __attribute__((ext_vector_type(4))) float f32x4;

typedef __attribute__((address_space(3))) unsigned lds_u32_t;
typedef const __attribute__((address_space(1))) unsigned glb_u32_t;

__device__ __forceinline__ unsigned short f2bf(float f) {
    unsigned u = __builtin_bit_cast(unsigned, f);
    u += 0x7FFFu + ((u >> 16) & 1u);
    return (unsigned short)(u >> 16);
}
__device__ __forceinline__ float bf2f(unsigned short s) {
    unsigned u = (unsigned)s << 16;
    return __builtin_bit_cast(float, u);
}
__device__ __forceinline__ void gll16(const u16* g, u16* lds) {
    __builtin_amdgcn_global_load_lds((glb_u32_t*)g, (lds_u32_t*)lds, 16, 0, 0);
}
__device__ __forceinline__ void pair_decode(int pair, int& ti, int& tj) {
    ti = (int)((sqrtf(8.f * pair + 1.f) - 1.f) * 0.5f);
    if ((ti + 1) * (ti + 2) / 2 <= pair) ++ti;
    if (ti * (ti + 1) / 2 > pair) --ti;
    tj = pair - ti * (ti + 1) / 2;
}

// ---------------- final GEMM: 256^2, BK=32, 3-buf counted-vmcnt ----------------
// C[m][n] = sum_k A[m][k]*B[n][k], row-major bf16, fp32 out.
// 512 thr = 8 waves (2x4), per-wave 128x64 output. LDS 96 KiB (3 bufs x 32 KB).
// Pipeline depth 2: stage(tt+2) issued during compute(tt); bottom-of-loop
// waits vmcnt(4) (= tile tt+1's loads done, tile tt+2 still in flight).
// Read-side slot swizzle kg^((fr>>1)&3) with matching inverse on global src.
__global__ __launch_bounds__(512) void gemm256_bf16(
    const u16* __restrict__ A, const u16* __restrict__ B, float* __restrict__ C,
    int K, int lda, int ldb, int ldc, long sA, long sB, long sC)
{
    __shared__ u16 lds[3][2][256 * 32];

    const int p = blockIdx.x;
    const int l = (p & 7) * 64 + (p >> 3);   // XCD swizzle: one batch per XCD
    const int bz = l >> 6;
    const int bm0 = ((l >> 2) & 15) * 256;
    const int bn0 = (l & 3) * 256;

    const int t = threadIdx.x, lane = t & 63, wave = t >> 6;
    const int wm = (wave >> 2) * 128, wn = (wave & 3) * 64;
    const int fr = lane & 15, kg = lane >> 4;
    const int xr = (fr >> 1) & 3;            // per-lane read-slot xor

    const u16* Ag = A + (long)bz * sA + (long)bm0 * lda;
    const u16* Bg = B + (long)bz * sB + (long)bn0 * ldb;

    f32x4 acc[8][4];
#pragma unroll
    for (int i = 0; i < 8; ++i)
#pragma unroll
        for (int j = 0; j < 4; ++j) acc[i][j] = (f32x4){0.f, 0.f, 0.f, 0.f};

    const int NT = K >> 5;                   // 32 K-tiles

    auto stage = [&](int tt, int bsel) {     // 4 gll16/thread
#pragma unroll
        for (int r = 0; r < 2; ++r) {
            const int idx = t + r * 512;     // 0..1023 16B-chunks
            const int row = idx >> 2;        // 0..255
            const int kq = idx & 3;
            const int ks = (kq ^ ((row >> 1) & 3)) << 3;   // inverse swizzle (shorts)
            gll16(Ag + (long)row * lda + tt * 32 + ks, &lds[bsel][0][idx * 8]);
            gll16(Bg + (long)row * ldb + tt * 32 + ks, &lds[bsel][1][idx * 8]);
        }
    };

    stage(0, 0);
    stage(1, 1);
    asm volatile("s_waitcnt vmcnt(4)" ::: "memory");   // buf0 resident
    __builtin_amdgcn_s_barrier();

    for (int tt = 0; tt < NT; ++tt) {
        const int cur = tt % 3;
        if (tt + 2 < NT) stage(tt + 2, (tt + 2) % 3);

        const u16* As = &lds[cur][0][0];
        const u16* Bs = &lds[cur][1][0];
        const int ko = ((kg ^ xr) << 3);
        short8v bf[4];
#pragma unroll
        for (int nt = 0; nt < 4; ++nt)
            bf[nt] = *(const short8v*)&Bs[(wn + nt * 16 + fr) * 32 + ko];
#pragma unroll
        for (int mt = 0; mt < 8; ++mt) {
            short8v af = *(const short8v*)&As[(wm + mt * 16 + fr) * 32 + ko];
#pragma unroll
            for (int nt = 0; nt < 4; ++nt)
                acc[mt][nt] = __builtin_amdgcn_mfma_f32_16x16x32_bf16(af, bf[nt], acc[mt][nt], 0, 0, 0);
        }

        if (tt + 1 < NT) {
            if (tt + 2 < NT) asm volatile("s_waitcnt vmcnt(4)" ::: "memory");
            else             asm volatile("s_waitcnt vmcnt(0)" ::: "memory");
            __builtin_amdgcn_s_barrier();    // tile tt+1 resident for all waves
        }
    }

    // C/D layout (m89-verified): col = lane&15, row = (lane>>4)*4 + q
#pragma unroll
    for (int mt = 0; mt < 8; ++mt)
#pragma unroll
        for (int nt = 0; nt < 4; ++nt)
#pragma unroll
            for (int q = 0; q < 4; ++q) {
                const int row = bm0 + wm + mt * 16 + kg * 4 + q;
                const int col = bn0 + wn + nt * 16 + fr;
                C[(long)bz * sC + (long)row * ldc + col] = acc[mt][nt][q];
            }
}

// ---------------- Gram split-K kernel ----------------
__global__ __launch_bounds__(256) void gram_splitk(
    const u16* __restrict__ xth, const u16* __restrict__ xtl, float* __restrict__ P)
{
    __shared__ u16 As[2 * 128 * 32];
    __shared__ u16 Bs[2 * 128 * 32];

    const int l = ((blockIdx.x & 7) * 144) + (blockIdx.x >> 3);
    const int batch = l / 144;
    const int rem = l - batch * 144;
    const int chunk = rem / 36;
    const int pair = rem - chunk * 36;
    int ti, tj;
    pair_decode(pair, ti, tj);

    const int t = threadIdx.x, lane = t & 63, wave = t >> 6;
    const int wm = (wave >> 1) * 64, wn = (wave & 1) * 64;
    const int fr = lane & 15, kg = lane >> 4;

    const u16* Agh = xth + ((long)batch * D_ + ti * 128) * S_ + chunk * 1024;
    const u16* Bgh = xth + ((long)batch * D_ + tj * 128) * S_ + chunk * 1024;
    const u16* Agl = xtl + ((long)batch * D_ + ti * 128) * S_ + chunk * 1024;
    const u16* Bgl = xtl + ((long)batch * D_ + tj * 128) * S_ + chunk * 1024;

    f32x4 acc[4][4];
#pragma unroll
    for (int i = 0; i < 4; ++i)
#pragma unroll
        for (int j = 0; j < 4; ++j) acc[i][j] = (f32x4){0.f, 0.f, 0.f, 0.f};

    for (int k0 = 0; k0 < 1024; k0 += 32) {
        if (k0) __syncthreads();
#pragma unroll
        for (int r = 0; r < 2; ++r) {
            const int off = r * 2048 + t * 8;
            const int row = off >> 5, kc = off & 31;
            gll16(Agh + (long)row * S_ + k0 + kc, As + off);
            gll16(Bgh + (long)row * S_ + k0 + kc, Bs + off);
            gll16(Agl + (long)row * S_ + k0 + kc, As + 4096 + off);
            gll16(Bgl + (long)row * S_ + k0 + kc, Bs + 4096 + off);
        }
        __syncthreads();

        const int ao = (wm + fr) * 32 + kg * 8;
        const int bo = (wn + fr) * 32 + kg * 8;
        short8v a[4], b[4];
#pragma unroll
        for (int mt = 0; mt < 4; ++mt) a[mt] = *(const short8v*)&As[ao + mt * 512];
#pragma unroll
        for (int nt = 0; nt < 4; ++nt) b[nt] = *(const short8v*)&Bs[bo + nt * 512];
#pragma unroll
        for (int mt = 0; mt < 4; ++mt)
#pragma unroll
            for (int nt = 0; nt < 4; ++nt)
                acc[mt][nt] = __builtin_amdgcn_mfma_f32_16x16x32_bf16(a[mt], b[nt], acc[mt][nt], 0, 0, 0);
        {
            short8v bl[4];
#pragma unroll
            for (int nt = 0; nt < 4; ++nt) bl[nt] = *(const short8v*)&Bs[4096 + bo + nt * 512];
#pragma unroll
            for (int mt = 0; mt < 4; ++mt)
#pragma unroll
                for (int nt = 0; nt < 4; ++nt)
                    acc[mt][nt] = __builtin_amdgcn_mfma_f32_16x16x32_bf16(a[mt], bl[nt], acc[mt][nt], 0, 0, 0);
#pragma unroll
            for (int mt = 0; mt < 4; ++mt) a[mt] = *(const short8v*)&As[4096 + ao + mt * 512];
#pragma unroll
            for (int mt = 0; mt < 4; ++mt)
#pragma unroll
                for (int nt = 0; nt < 4; ++nt)
                    acc[mt][nt] = __builtin_amdgcn_mfma_f32_16x16x32_bf16(a[mt], b[nt], acc[mt][nt], 0, 0, 0);
        }
    }

    float* out = P + (((long)chunk * B_ + batch) * 36 + pair) * 16384;
#pragma unroll
    for (int mt = 0; mt < 4; ++mt)
#pragma unroll
        for (int nt = 0; nt < 4; ++nt)
#pragma unroll
            for (int q = 0; q < 4; ++q)
                out[(wm + mt * 16 + kg * 4 + q) * 128 + wn + nt * 16 + fr] = acc[mt][nt][q];
}

// ---------------- reduce partials + convert + mirror ----------------
__global__ __launch_bounds__(256) void reduce_mirror(
    const float* __restrict__ P, u16* __restrict__ Gh, u16* __restrict__ Gl)
{
    __shared__ u16 th[128][132];
    __shared__ u16 tl[128][132];
    const int pair = blockIdx.x, b = blockIdx.y;
    int ti, tj;
    pair_decode(pair, ti, tj);
    const int t = threadIdx.x;
    const long tile = 16384;
    const long cs = (long)B_ * 36 * tile;
    const float* base = P + ((long)b * 36 + pair) * tile;
    u16* GhB = Gh + (long)b * D_ * D_;
    u16* GlB = Gl + (long)b * D_ * D_;

#pragma unroll
    for (int e = 0; e < 16; ++e) {
        const int idx = e * 1024 + t * 4;
        float4 s0 = *(const float4*)&base[idx];
        float4 s1 = *(const float4*)&base[cs + idx];
        float4 s2 = *(const float4*)&base[2 * cs + idx];
        float4 s3 = *(const float4*)&base[3 * cs + idx];
        float f[4] = {s0.x + s1.x + s2.x + s3.x, s0.y + s1.y + s2.y + s3.y,
                      s0.z + s1.z + s2.z + s3.z, s0.w + s1.w + s2.w + s3.w};
        const int r = idx >> 7, c = idx & 127;
        short4v hv, lv;
#pragma unroll
        for (int j = 0; j < 4; ++j) {
            const unsigned short h = f2bf(f[j]);
            hv[j] = (short)h;
            lv[j] = (short)f2bf(f[j] - bf2f(h));
        }
        *(short4v*)&GhB[(long)(ti * 128 + r) * D_ + tj * 128 + c] = hv;
        *(short4v*)&GlB[(long)(ti * 128 + r) * D_ + tj * 128 + c] = lv;
        if (ti != tj) {
#pragma unroll
            for (int j = 0; j < 4; ++j) {
                th[c + j][r] = hv[j];
                tl[c + j][r] = lv[j];
            }
        }
    }
    if (ti != tj) {
        __syncthreads();
#pragma unroll
        for (int e = 0; e < 16; ++e) {
            const int idx = e * 1024 + t * 4;
            const int r = idx >> 7, c = idx & 127;
            short4v hv = *(const short4v*)&th[r][c];
            short4v lv = *(const short4v*)&tl[r][c];
            *(short4v*)&GhB[(long)(tj * 128 + r) * D_ + ti * 128 + c] = hv;
            *(short4v*)&GlB[(long)(tj * 128 + r) * D_ + ti * 128 + c] = lv;
        }
    }
}

// ---------------- 128^2 MFMA GEMM (m97 structure) ----------------
template<int OUT, bool SPLIT>
__global__ __launch_bounds__(256) void gemm_bf16(
    const u16* __restrict__ Ah, const u16* __restrict__ Al,
    const u16* __restrict__ Bh, const u16* __restrict__ Bl,
    float* __restrict__ Cf, u16* __restrict__ Ch,
    int K, int lda, int ldb, int ldc, long sA, long sB, long sC)
{
    __shared__ u16 As[(SPLIT ? 2 : 1) * 128 * 32];
    __shared__ u16 Bs[(SPLIT ? 2 : 1) * 128 * 32];

    const int bn0 = blockIdx.x * 128, bm0 = blockIdx.y * 128;
    const int t = threadIdx.x, lane = t & 63, wave = t >> 6;
    const int wm = (wave >> 1) * 64, wn = (wave & 1) * 64;
    const int fr = lane & 15, kg = lane >> 4;

    const u16* Agh = Ah + (long)blockIdx.z * sA + (long)bm0 * lda;
    const u16* Bgh = Bh + (long)blockIdx.z * sB + (long)bn0 * ldb;
    const u16* Agl = SPLIT ? (Al + (long)blockIdx.z * sA + (long)bm0 * lda) : nullptr;
    const u16* Bgl = SPLIT ? (Bl + (long)blockIdx.z * sB + (long)bn0 * ldb) : nullptr;

    f32x4 acc[4][4];
#pragma unroll
    for (int i = 0; i < 4; ++i)
#pragma unroll
        for (int j = 0; j < 4; ++j) acc[i][j] = (f32x4){0.f, 0.f, 0.f, 0.f};

    for (int k0 = 0; k0 < K; k0 += 32) {
        if (k0) __syncthreads();
#pragma unroll
        for (int r = 0; r < 2; ++r) {
            const int off = r * 2048 + t * 8;
            const int row = off >> 5, kc = off & 31;
            gll16(Agh + (long)row * lda + k0 + kc, As + off);
            gll16(Bgh + (long)row * ldb + k0 + kc, Bs + off);
            if (SPLIT) {
                gll16(Agl + (long)row * lda + k0 + kc, As + 4096 + off);
                gll16(Bgl + (long)row * ldb + k0 + kc, Bs + 4096 + off);
            }
        }
        __syncthreads();

        const int ao = (wm + fr) * 32 + kg * 8;
        const int bo = (wn + fr) * 32 + kg * 8;
        short8v a[4], b[4];
#pragma unroll
        for (int mt = 0; mt < 4; ++mt) a[mt] = *(const short8v*)&As[ao + mt * 512];
#pragma unroll
        for (int nt = 0; nt < 4; ++nt) b[nt] = *(const short8v*)&Bs[bo + nt * 512];
#pragma unroll
        for (int mt = 0; mt < 4; ++mt)
#pragma unroll
            for (int nt = 0; nt < 4; ++nt)
                acc[mt][nt] = __builtin_amdgcn_mfma_f32_16x16x32_bf16(a[mt], b[nt], acc[mt][nt], 0, 0, 0);
        if (SPLIT) {
            short8v bl[4];
#pragma unroll
            for (int nt = 0; nt < 4; ++nt) bl[nt] = *(const short8v*)&Bs[4096 + bo + nt * 512];
#pragma unroll
            for (int mt = 0; mt < 4; ++mt)
#pragma unroll
                for (int nt = 0; nt < 4; ++nt)
                    acc[mt][nt] = __builtin_amdgcn_mfma_f32_16x16x32_bf16(a[mt], bl[nt], acc[mt][nt], 0, 0, 0);
#pragma unroll
            for (int mt = 0; mt < 4; ++mt) a[mt] = *(const short8v*)&As[4096 + ao + mt * 512];
#pragma unroll
            for (int mt = 0; mt < 4; ++mt)
#pragma unroll
                for (int nt = 0; nt < 4; ++nt)
                    acc[mt][nt] = __builtin_amdgcn_mfma_f32_16x16x32_bf16(a[mt], b[nt], acc[mt][nt], 0, 0, 0);
        }
    }

#pragma unroll
    for (int mt = 0; mt < 4; ++mt)
#pragma unroll
        for (int nt = 0; nt < 4; ++nt)
#pragma unroll
            for (int q = 0; q < 4; ++q) {
                const int row = bm0 + wm + mt * 16 + kg * 4 + q;
                const int col = bn0 + wn + nt * 16 + fr;
                const float v = acc[mt][nt][q];
                const long idx = (long)blockIdx.z * sC + (long)row * ldc + col;
                if (OUT == 0) Cf[idx] = v;
                else Ch[idx] = f2bf(v);
            }
}

// ---------------- prepack: x -> transposed bf16 hi/lo (+ optional xh) ----------------
template<bool WITH_XH>
__global__ __launch_bounds__(256) void prepack_xt(
    const float* __restrict__ x, u16* __restrict__ xth, u16* __restrict__ xtl,
    u16* __restrict__ xh)
{
    __shared__ float tile[64][65];
    const int d0 = blockIdx.x * 64, s0 = blockIdx.y * 64, b = blockIdx.z;
    const float* xb = x + (long)b * S_ * D_;
    const int t = threadIdx.x;
    const int sr = t >> 4, dc = (t & 15) * 4;
#pragma unroll
    for (int r = 0; r < 4; ++r) {
        const int s = sr + r * 16;
        float4 v = *(const float4*)&xb[(long)(s0 + s) * D_ + d0 + dc];
        tile[dc + 0][s] = v.x;
        tile[dc + 1][s] = v.y;
        tile[dc + 2][s] = v.z;
        tile[dc + 3][s] = v.w;
        if (WITH_XH) {
            short4v hv = {(short)f2bf(v.x), (short)f2bf(v.y), (short)f2bf(v.z), (short)f2bf(v.w)};
            *(short4v*)&xh[((long)b * S_ + s0 + s) * D_ + d0 + dc] = hv;
        }
    }
    __syncthreads();
    const int dr = t >> 4, sc = (t & 15) * 4;
    u16* th = xth + (long)b * D_ * S_;
    u16* tl = xtl + (long)b * D_ * S_;
#pragma unroll
    for (int r = 0; r < 4; ++r) {
        const int d = dr + r * 16;
        short4v hv, lv;
#pragma unroll
        for (int j = 0; j < 4; ++j) {
            const float v = tile[d][sc + j];
            const unsigned short h = f2bf(v);
            hv[j] = (short)h;
            lv[j] = (short)f2bf(v - bf2f(h));
        }
        *(short4v*)&th[(long)(d0 + d) * S_ + s0 + sc] = hv;
        *(short4v*)&tl[(long)(d0 + d) * S_ + s0 + sc] = lv;
    }
}

// ---------------- generic fp32 -> bf16 convert ----------------
template<bool SP>
__global__ __launch_bounds__(256) void convert_bf16(
    const float* __restrict__ in, u16* __restrict__ h, u16* __restrict__ l, long n)
{
    const long i = ((long)blockIdx.x * 256 + threadIdx.x) * 4;
    if (i >= n) return;
    float4 v = *(const float4*)&in[i];
    float f[4] = {v.x, v.y, v.z, v.w};
    short4v hv, lv;
#pragma unroll
    for (int j = 0; j < 4; ++j) {
        const unsigned short hh = f2bf(f[j]);
        hv[j] = (short)hh;
        lv[j] = (short)f2bf(f[j] - bf2f(hh));
    }
    *(short4v*)&h[i] = hv;
    if (SP) *(short4v*)&l[i] = lv;
}

// ---------------- scores + softmax (fp32) ----------------
__global__ __launch_bounds__(256) void scores_softmax(
    const float* __restrict__ Mt, const float* __restrict__ Wk, float* __restrict__ att)
{
    __shared__ float Ms2[64][65];
    __shared__ float Ks[64][65];
    __shared__ float Sm[64][65];
    __shared__ float rowm[64], rows[64];
    const int bh = blockIdx.x;
    const int b = bh >> 4, h = bh & 15;
    const float* Mbase = Mt + (long)b * D_ * D_ + h * 64;
    const float* Kbase = Wk + (long)h * 64 * D_;
    const int t = threadIdx.x;
    const int e = t & 63, dg = t >> 6;

    float acc[16];
#pragma unroll
    for (int i = 0; i < 16; ++i) acc[i] = 0.f;

    for (int jc = 0; jc < D_; jc += 64) {
        __syncthreads();
        {
            int row = t >> 2, c4 = (t & 3) * 16;
#pragma unroll
            for (int r = 0; r < 4; ++r) {
                float4 v = *(const float4*)&Mbase[(long)(jc + row) * D_ + c4 + r * 4];
                Ms2[row][c4 + r * 4 + 0] = v.x;
                Ms2[row][c4 + r * 4 + 1] = v.y;
                Ms2[row][c4 + r * 4 + 2] = v.z;
                Ms2[row][c4 + r * 4 + 3] = v.w;
                float4 w = *(const float4*)&Kbase[(long)row * D_ + jc + c4 + r * 4];
                Ks[row][c4 + r * 4 + 0] = w.x;
                Ks[row][c4 + r * 4 + 1] = w.y;
                Ks[row][c4 + r * 4 + 2] = w.z;
                Ks[row][c4 + r * 4 + 3] = w.w;
            }
        }
        __syncthreads();
#pragma unroll 8
        for (int jj = 0; jj < 64; ++jj) {
            float kv = Ks[e][jj];
#pragma unroll
            for (int dd = 0; dd < 16; ++dd)
                acc[dd] = fmaf(Ms2[jj][dg * 16 + dd], kv, acc[dd]);
        }
    }
    __syncthreads();
#pragma unroll
    for (int dd = 0; dd < 16; ++dd) Sm[dg * 16 + dd][e] = acc[dd] * 0.125f;
    __syncthreads();
    if (t < 64) {
        float m = -1e30f;
        for (int ee = 0; ee < 64; ++ee) m = fmaxf(m, Sm[t][ee]);
        float s = 0.f;
        for (int ee = 0; ee < 64; ++ee) s += expf(Sm[t][ee] - m);
        rowm[t] = m;
        rows[t] = 1.0f / s;
    }
    __syncthreads();
    float* abase = att + (long)bh * 64 * 64;
#pragma unroll
    for (int dd = 0; dd < 16; ++dd) {
        int d = dg * 16 + dd;
        abase[d * 64 + e] = expf(Sm[d][e] - rowm[d]) * rows[d];
    }
}

// ---------------- T build (fp32 compute, bf16 out) ----------------
__global__ __launch_bounds__(256) void build_T(
    const float* __restrict__ Wv, const float* __restrict__ att, u16* __restrict__ T)
{
    __shared__ float atts[64][65];
    __shared__ float Wvs[64][65];
    const int i0 = blockIdx.x * 64, h = blockIdx.y, b = blockIdx.z;
    const int t = threadIdx.x;
    {
        int row = t >> 2, c4 = (t & 3) * 16;
        const float* ab = att + (((long)b * H_ + h) * 64) * 64;
        const float* wb = Wv + (long)h * 64 * D_ + i0;
#pragma unroll
        for (int r = 0; r < 4; ++r) {
            float4 v = *(const float4*)&ab[row * 64 + c4 + r * 4];
            atts[row][c4 + r * 4 + 0] = v.x;
            atts[row][c4 + r * 4 + 1] = v.y;
            atts[row][c4 + r * 4 + 2] = v.z;
            atts[row][c4 + r * 4 + 3] = v.w;
            float4 w = *(const float4*)&wb[(long)row * D_ + c4 + r * 4];
            Wvs[row][c4 + r * 4 + 0] = w.x;
            Wvs[row][c4 + r * 4 + 1] = w.y;
            Wvs[row][c4 + r * 4 + 2] = w.z;
            Wvs[row][c4 + r * 4 + 3] = w.w;
        }
    }
    __syncthreads();
    const int e = t & 63, ig = t >> 6;
    float acc[16];
#pragma unroll
    for (int i = 0; i < 16; ++i) acc[i] = 0.f;
#pragma unroll 8
    for (int d = 0; d < 64; ++d) {
        float av = atts[d][e];
#pragma unroll
        for (int ii = 0; ii < 16; ++ii)
            acc[ii] = fmaf(Wvs[d][ig * 16 + ii], av, acc[ii]);
    }
    u16* Tb = T + (long)b * D_ * D_;
#pragma unroll
    for (int ii = 0; ii < 16; ++ii) {
        int i = i0 + ig * 16 + ii;
        Tb[(long)i * D_ + h * 64 + e] = f2bf(acc[ii]);
    }
}

extern "C" void kernel_launch(void* const* d_in, const int* in_sizes, int n_in,
                              void* d_out, int out_size, void* d_ws, size_t ws_size,
                              hipStream_t stream) {
    const float* x  = (const float*)d_in[0];
    const float* Wq = (const float*)d_in[1];
    const float* Wk = (const float*)d_in[2];
    const float* Wv = (const float*)d_in[3];
    const float* Wo = (const float*)d_in[4];
    float* out = (float*)d_out;

    const long MM = (long)D_ * D_;          // 1,048,576
    const long XE = (long)B_ * S_ * D_;     // 33,554,432
    const long GE = (long)B_ * MM;          // 8,388,608
    const long PB = 4L * B_ * 36 * 16384 * 4;  // 75,497,472 bytes

    u16* xth = (u16*)d_out;                 // dead before final GEMM writes out
    u16* xtl = xth + XE;

    const bool FUSED = ws_size >= (size_t)(XE * 2 + PB + GE * 2 * 2 +
                                           (long)B_ * H_ * 64 * 64 * 4 + MM * 2 * 3);

    u16 *xh, *Gh, *Gl, *Wqh, *Wql, *Woh;
    float *P, *Mt, *att;
    if (FUSED) {
        // xh | P (Mt aliases P) | Gh | Gl | att | Wqh | Wql | Woh   (184.5 MB)
        char* w = (char*)d_ws;
        xh  = (u16*)w;        w += XE * 2;
        P   = (float*)w;
        Mt  = (float*)w;      w += PB;
        Gh  = (u16*)w;        w += GE * 2;
        Gl  = (u16*)w;        w += GE * 2;
        att = (float*)w;      w += (long)B_ * H_ * 64 * 64 * 4;
        Wqh = (u16*)w;        w += MM * 2;
        Wql = (u16*)w;        w += MM * 2;
        Woh = (u16*)w;
    } else {
        // R5 layout: [P | xh+Mt] overlap region, then Gh/Gl/att/W   (142.6 MB)
        char* w = (char*)d_ws;
        P   = (float*)w;
        xh  = (u16*)w;
        Mt  = (float*)(w + XE * 2);
        w += XE * 2 + GE * 4;
        Gh  = (u16*)w;        w += GE * 2;
        Gl  = (u16*)w;        w += GE * 2;
        att = (float*)w;      w += (long)B_ * H_ * 64 * 64 * 4;
        Wqh = (u16*)w;        w += MM * 2;
        Wql = (u16*)w;        w += MM * 2;
        Woh = (u16*)w;
    }
    u16* Th  = Gh;
    u16* Eth = Gl;

    // 1. prepacks
    if (FUSED)
        prepack_xt<true ><<<dim3(D_ / 64, S_ / 64, B_), 256, 0, stream>>>(x, xth, xtl, xh);
    else
        prepack_xt<false><<<dim3(D_ / 64, S_ / 64, B_), 256, 0, stream>>>(x, xth, xtl, nullptr);
    convert_bf16<true ><<<MM / 1024, 256, 0, stream>>>(Wq, Wqh, Wql, MM);
    convert_bf16<false><<<MM / 1024, 256, 0, stream>>>(Wo, Woh, nullptr, MM);

    // 2. Gram split-K -> P
    gram_splitk<<<36 * 4 * B_, 256, 0, stream>>>(xth, xtl, P);

    // 3. reduce + mirror -> Gh/Gl
    reduce_mirror<<<dim3(36, B_), 256, 0, stream>>>(P, Gh, Gl);

    // 4. xh standalone (only if not fused; P dead now)
    if (!FUSED)
        convert_bf16<false><<<XE / 1024, 256, 0, stream>>>(x, xh, nullptr, XE);

    // 5. Mt[i][j] = sum_k G[i][k] Wq[j][k]  (split) -> fp32 (P dead)
    gemm_bf16<0, true><<<dim3(8, 8, B_), 256, 0, stream>>>(
        Gh, Gl, Wqh, Wql, Mt, nullptr,
        D_, D_, D_, D_, MM, 0, MM);

    // 6. scores + softmax
    scores_softmax<<<B_ * H_, 256, 0, stream>>>(Mt, Wk, att);

    // 7. T (bf16) -> Th (aliases Gh; G consumed)
    build_T<<<dim3(D_ / 64, H_, B_), 256, 0, stream>>>(Wv, att, Th);

    // 8. Et[j][i] = sum_k Wo[j][k] T[i][k] -> bf16 (aliases Gl)
    gemm_bf16<1, false><<<dim3(8, 8, B_), 256, 0, stream>>>(
        Woh, nullptr, Th, nullptr, nullptr, Eth,
        D_, D_, D_, D_, 0, MM, MM);

    // 9. out[s][j] = sum_i x[s][i] Et[j][i]  -- 3-buf counted-vmcnt pipeline
    gemm256_bf16<<<(S_ / 256) * (D_ / 256) * B_, 512, 0, stream>>>(
        xh, Eth, out,
        D_, D_, D_, D_, (long)S_ * D_, MM, (long)S_ * D_);
}